// Round 1
// baseline (731.499 us; speedup 1.0000x reference)
//
#include <hip/hip_runtime.h>
#include <math.h>

#define N_ENT 100000
#define N_USR 50000
#define N_EDGE 1000000
#define TEMPC 0.2f
#define KG_BLOCKS (N_ENT / 4)   // 25000, exact
#define UI_BLOCKS (N_USR / 4)   // 12500, exact

// fused-kernel block ranges
#define TB_BLOCKS 6250   // ceil(N_ENT*64/4 / 256) : bf16 convert (float4 granules)
#define CNT_BLOCKS 489   // ceil(N_EDGE/8 / 256) : count, 8 edges/thread
#define SC_BLOCKS 196    // ceil(N_USR / 256)
#define BUILD_BLOCKS 489 // ceil(N_EDGE/8 / 256)
#define REL2_BLOCKS 391  // ceil(N_ENT / 256)

typedef unsigned short ushort_t;

__device__ __forceinline__ float waveReduceSum(float x) {
#pragma unroll
  for (int d = 32; d > 0; d >>= 1) x += __shfl_xor(x, d);
  return x;
}
__device__ __forceinline__ float waveReduceMax(float x) {
#pragma unroll
  for (int d = 32; d > 0; d >>= 1) x = fmaxf(x, __shfl_xor(x, d));
  return x;
}
__device__ __forceinline__ int waveReduceSumI(int x) {
#pragma unroll
  for (int d = 32; d > 0; d >>= 1) x += __shfl_xor(x, d);
  return x;
}
__device__ __forceinline__ float bf2f(unsigned int u16) {
  union { unsigned int i; float f; } v;
  v.i = u16 << 16;
  return v.f;
}
__device__ __forceinline__ ushort_t f2bf(float f) {
  union { unsigned int i; float f; } v;
  v.f = f;
  unsigned int u = v.i;
  u = (u + 0x7FFFu + ((u >> 16) & 1u)) >> 16;
  return (ushort_t)u;
}
// wave-uniform broadcast via v_readlane -> SGPR (cheap scalar addressing downstream)
__device__ __forceinline__ int rl(int v, int l) { return __builtin_amdgcn_readlane(v, l); }
__device__ __forceinline__ float rlf(float v, int l) {
  return __int_as_float(__builtin_amdgcn_readlane(__float_as_int(v), l));
}

// ============ K1: bf16 convert | edge count (8/thr) | prep | sc(user) ============
__global__ void k_pre(const float* __restrict__ ent0, ushort_t* __restrict__ ent0bf,
                      const int* __restrict__ head, const int* __restrict__ uir,
                      const int* __restrict__ etype,
                      int* __restrict__ cnt_u, int* __restrict__ cnt9,
                      const float* __restrict__ weight, const float* __restrict__ kgW,
                      const float* __restrict__ disen,
                      float* __restrict__ V, float* __restrict__ wsq,
                      float* __restrict__ dw, float* __restrict__ cor_out,
                      const float* __restrict__ user_emb, const float* __restrict__ latent,
                      float4* __restrict__ sc4a) {
  int bid = blockIdx.x;
  if (bid < TB_BLOCKS) {
    int i = bid * 256 + threadIdx.x;
    if (i < N_ENT * 16) {
      float4 v = ((const float4*)ent0)[i];
      ushort4 o;
      o.x = f2bf(v.x); o.y = f2bf(v.y); o.z = f2bf(v.z); o.w = f2bf(v.w);
      ((ushort4*)ent0bf)[i] = o;
    }
  } else if (bid < TB_BLOCKS + CNT_BLOCKS) {
    int i0 = ((bid - TB_BLOCKS) * 256 + threadIdx.x) * 8;
    if (i0 < N_EDGE) {
      int4 ha = *(const int4*)(head + i0), hb = *(const int4*)(head + i0 + 4);
      int4 ea = *(const int4*)(etype + i0), eb = *(const int4*)(etype + i0 + 4);
      int4 ua = *(const int4*)(uir + i0), ub = *(const int4*)(uir + i0 + 4);
      atomicAdd(&cnt9[ha.x * 9 + (ea.x - 1)], 1);
      atomicAdd(&cnt9[ha.y * 9 + (ea.y - 1)], 1);
      atomicAdd(&cnt9[ha.z * 9 + (ea.z - 1)], 1);
      atomicAdd(&cnt9[ha.w * 9 + (ea.w - 1)], 1);
      atomicAdd(&cnt9[hb.x * 9 + (eb.x - 1)], 1);
      atomicAdd(&cnt9[hb.y * 9 + (eb.y - 1)], 1);
      atomicAdd(&cnt9[hb.z * 9 + (eb.z - 1)], 1);
      atomicAdd(&cnt9[hb.w * 9 + (eb.w - 1)], 1);
      atomicAdd(&cnt_u[ua.x], 1);
      atomicAdd(&cnt_u[ua.y], 1);
      atomicAdd(&cnt_u[ua.z], 1);
      atomicAdd(&cnt_u[ua.w], 1);
      atomicAdd(&cnt_u[ub.x], 1);
      atomicAdd(&cnt_u[ub.y], 1);
      atomicAdd(&cnt_u[ub.z], 1);
      atomicAdd(&cnt_u[ub.w], 1);
    }
  } else if (bid == TB_BLOCKS + CNT_BLOCKS) {
    // ---- prep: V=(W W^T)w_r via T-factorization, wsq, dw, cor ----
    __shared__ float T[9 * 64];
    __shared__ float sm[4 * 9];
    int tid = threadIdx.x;
    for (int e = tid; e < 9 * 64; e += 256) {
      int r = e >> 6, d = e & 63;
      float s = 0.f;
      for (int k = 0; k < 64; ++k) s += kgW[k * 64 + d] * weight[r * 64 + k];
      T[e] = s;
    }
    if (tid < 4) {
      float m = -INFINITY;
      for (int r = 0; r < 9; ++r) m = fmaxf(m, disen[tid * 9 + r]);
      float den = 0.f;
      float ex[9];
      for (int r = 0; r < 9; ++r) { ex[r] = expf(disen[tid * 9 + r] - m); den += ex[r]; }
      for (int r = 0; r < 9; ++r) sm[tid * 9 + r] = ex[r] / den;
    }
    __syncthreads();
    for (int e = tid; e < 9 * 64; e += 256) {
      int r = e >> 6, i = e & 63;
      float s = 0.f;
      for (int d = 0; d < 64; ++d) s += kgW[i * 64 + d] * T[r * 64 + d];
      V[e] = s;
    }
    if (tid < 9) {
      float s = 0.f;
      for (int c = 0; c < 64; ++c) { float w = weight[tid * 64 + c]; s += w * w; }
      wsq[tid] = s;
    }
    for (int e = tid; e < 4 * 64; e += 256) {
      int f = e >> 6, c = e & 63;
      float s = 0.f;
      for (int r = 0; r < 9; ++r) s += sm[f * 9 + r] * weight[r * 64 + c];
      dw[e] = s;
    }
    if (tid == 0) {
      float rowsum[4];
      for (int f = 0; f < 4; ++f) {
        float s = 0.f;
        for (int j = 0; j < 9; ++j) s += disen[f * 9 + j];
        rowsum[f] = s;
      }
      float cor = 0.f;
      for (int i = 0; i < 9; ++i) {
        float n2 = 0.f, ttl = 0.f;
        for (int f = 0; f < 4; ++f) {
          float v = disen[f * 9 + i];
          n2 += v * v;
          ttl += v * rowsum[f];
        }
        float nrm = sqrtf(n2);
        float pos = 0.f;
        for (int f = 0; f < 4; ++f) {
          float v = disen[f * 9 + i] / nrm;
          pos += v * v;
        }
        cor += (ttl - pos) / TEMPC;
      }
      *cor_out = cor;
    }
  } else {
    // ---- sc on user_emb -> sc4a ----
    __shared__ __align__(16) float lat[256];
    if (threadIdx.x < 256) lat[threadIdx.x] = latent[threadIdx.x];
    __syncthreads();
    int u = (bid - TB_BLOCKS - CNT_BLOCKS - 1) * 256 + threadIdx.x;
    if (u >= N_USR) return;
    float a0 = 0.f, a1 = 0.f, a2 = 0.f, a3 = 0.f;
    const float4* row = (const float4*)(user_emb + (size_t)u * 64);
#pragma unroll
    for (int q = 0; q < 16; ++q) {
      float4 v = row[q];
      float4 l0 = *(const float4*)(lat + 0 * 64 + q * 4);
      float4 l1 = *(const float4*)(lat + 1 * 64 + q * 4);
      float4 l2 = *(const float4*)(lat + 2 * 64 + q * 4);
      float4 l3 = *(const float4*)(lat + 3 * 64 + q * 4);
      a0 = fmaf(v.x, l0.x, a0); a0 = fmaf(v.y, l0.y, a0); a0 = fmaf(v.z, l0.z, a0); a0 = fmaf(v.w, l0.w, a0);
      a1 = fmaf(v.x, l1.x, a1); a1 = fmaf(v.y, l1.y, a1); a1 = fmaf(v.z, l1.z, a1); a1 = fmaf(v.w, l1.w, a1);
      a2 = fmaf(v.x, l2.x, a2); a2 = fmaf(v.y, l2.y, a2); a2 = fmaf(v.z, l2.z, a2); a2 = fmaf(v.w, l2.w, a2);
      a3 = fmaf(v.x, l3.x, a3); a3 = fmaf(v.y, l3.y, a3); a3 = fmaf(v.z, l3.z, a3); a3 = fmaf(v.w, l3.w, a3);
    }
    sc4a[u] = make_float4(a0, a1, a2, a3);
  }
}

// ============ K2: fused scan-reduce (head from cnt9 rowsums | ui) ============
__global__ void k_scanred(const int* __restrict__ cnt9, const int* __restrict__ cnt_u,
                          int* __restrict__ bsum_h, int* __restrict__ bsum_u, int nbh) {
  int b = blockIdx.x, tid = threadIdx.x;
  int s = 0;
  if (b < nbh) {
    int i0 = b * 1024 + tid * 4;
#pragma unroll
    for (int k = 0; k < 4; ++k)
      if (i0 + k < N_ENT) {
        int base = (i0 + k) * 9;
#pragma unroll
        for (int r = 0; r < 9; ++r) s += cnt9[base + r];
      }
  } else {
    int i0 = (b - nbh) * 1024 + tid * 4;
#pragma unroll
    for (int k = 0; k < 4; ++k)
      if (i0 + k < N_USR) s += cnt_u[i0 + k];
  }
  s = waveReduceSumI(s);
  __shared__ int l[4];
  int lane = tid & 63, wid = tid >> 6;
  if (lane == 0) l[wid] = s;
  __syncthreads();
  if (tid == 0) {
    int v = l[0] + l[1] + l[2] + l[3];
    if (b < nbh) bsum_h[b] = v; else bsum_u[b - nbh] = v;
  }
}

__global__ void k_scan_tops(int* bsA, int nA, int* bsB, int nB,
                            int* ptrA, int NA, int* ptrB, int NB, int total) {
  if (threadIdx.x == 0) {
    int a = 0;
    for (int i = 0; i < nA; ++i) { int t = bsA[i]; bsA[i] = a; a += t; }
    ptrA[NA] = total;
  }
  if (threadIdx.x == 1) {
    int a = 0;
    for (int i = 0; i < nB; ++i) { int t = bsB[i]; bsB[i] = a; a += t; }
    ptrB[NB] = total;
  }
}

// ============ K4: fused scan-final (head from cnt9 | ui) ============
__global__ void k_scanfin(const int* __restrict__ cnt9, const int* __restrict__ bsum_h,
                          const int* __restrict__ bsum_u,
                          int* __restrict__ head_ptr, int* __restrict__ head_cur,
                          int* __restrict__ ui_ptr, int* __restrict__ ui_cur, int nbh) {
  int b = blockIdx.x, tid = threadIdx.x;
  bool isH = (b < nbh);
  int bl = isH ? b : b - nbh;
  int n = isH ? N_ENT : N_USR;
  int i0 = bl * 1024 + tid * 4;
  int c[4];
  int s = 0;
  int loc[4];
#pragma unroll
  for (int k = 0; k < 4; ++k) {
    int v = 0;
    if (i0 + k < n) {
      if (isH) {
        int base = (i0 + k) * 9;
#pragma unroll
        for (int r = 0; r < 9; ++r) v += cnt9[base + r];
      } else {
        v = ui_cur[i0 + k];
      }
    }
    c[k] = v;
    loc[k] = s;
    s += v;
  }
  int lane = tid & 63, wid = tid >> 6;
  int x = s;
#pragma unroll
  for (int d = 1; d < 64; d <<= 1) {
    int y = __shfl_up(x, d);
    if (lane >= d) x += y;
  }
  __shared__ int l[4];
  if (lane == 63) l[wid] = x;
  __syncthreads();
  if (tid == 0) {
    int a = 0;
    for (int w = 0; w < 4; ++w) { int t = l[w]; l[w] = a; a += t; }
  }
  __syncthreads();
  int excl = x - s + l[wid] + (isH ? bsum_h[bl] : bsum_u[bl]);
#pragma unroll
  for (int k = 0; k < 4; ++k) {
    if (i0 + k < n) {
      int v = excl + loc[k];
      if (isH) {
        head_ptr[i0 + k] = v;
        head_cur[i0 + k] = v;
      } else {
        ui_ptr[i0 + k] = v;
        ui_cur[i0 + k] = v;
      }
    }
  }
}

// ============ K5: build (8/thr) | rel2 ============
__global__ void k_build_rel2(const int* __restrict__ head, const int* __restrict__ tail,
                             const int* __restrict__ etype,
                             const int* __restrict__ uir, const int* __restrict__ uic,
                             const float* __restrict__ uival,
                             int* __restrict__ cur_h, int* __restrict__ cur_u,
                             int* __restrict__ packed, int2* __restrict__ cv,
                             const ushort_t* __restrict__ ent0bf, const float* __restrict__ V,
                             const float* __restrict__ wsq, const int* __restrict__ cnt9,
                             float* __restrict__ rel2t) {
  if (blockIdx.x < BUILD_BLOCKS) {
    int i0 = (blockIdx.x * 256 + threadIdx.x) * 8;
    if (i0 >= N_EDGE) return;
    int4 ha = *(const int4*)(head + i0), hb = *(const int4*)(head + i0 + 4);
    int4 ta = *(const int4*)(tail + i0), tb4 = *(const int4*)(tail + i0 + 4);
    int4 ea = *(const int4*)(etype + i0), eb = *(const int4*)(etype + i0 + 4);
    int4 ua = *(const int4*)(uir + i0), ub = *(const int4*)(uir + i0 + 4);
    int4 ca = *(const int4*)(uic + i0), cb = *(const int4*)(uic + i0 + 4);
    float4 va = *(const float4*)(uival + i0), vb = *(const float4*)(uival + i0 + 4);
    int p0 = atomicAdd(&cur_h[ha.x], 1);
    int p1 = atomicAdd(&cur_h[ha.y], 1);
    int p2 = atomicAdd(&cur_h[ha.z], 1);
    int p3 = atomicAdd(&cur_h[ha.w], 1);
    int p4 = atomicAdd(&cur_h[hb.x], 1);
    int p5 = atomicAdd(&cur_h[hb.y], 1);
    int p6 = atomicAdd(&cur_h[hb.z], 1);
    int p7 = atomicAdd(&cur_h[hb.w], 1);
    int q0 = atomicAdd(&cur_u[ua.x], 1);
    int q1 = atomicAdd(&cur_u[ua.y], 1);
    int q2 = atomicAdd(&cur_u[ua.z], 1);
    int q3 = atomicAdd(&cur_u[ua.w], 1);
    int q4 = atomicAdd(&cur_u[ub.x], 1);
    int q5 = atomicAdd(&cur_u[ub.y], 1);
    int q6 = atomicAdd(&cur_u[ub.z], 1);
    int q7 = atomicAdd(&cur_u[ub.w], 1);
    packed[p0] = (ta.x & 0xFFFFF) | ((ea.x - 1) << 20);
    packed[p1] = (ta.y & 0xFFFFF) | ((ea.y - 1) << 20);
    packed[p2] = (ta.z & 0xFFFFF) | ((ea.z - 1) << 20);
    packed[p3] = (ta.w & 0xFFFFF) | ((ea.w - 1) << 20);
    packed[p4] = (tb4.x & 0xFFFFF) | ((eb.x - 1) << 20);
    packed[p5] = (tb4.y & 0xFFFFF) | ((eb.y - 1) << 20);
    packed[p6] = (tb4.z & 0xFFFFF) | ((eb.z - 1) << 20);
    packed[p7] = (tb4.w & 0xFFFFF) | ((eb.w - 1) << 20);
    cv[q0] = make_int2(ca.x, __float_as_int(va.x));
    cv[q1] = make_int2(ca.y, __float_as_int(va.y));
    cv[q2] = make_int2(ca.z, __float_as_int(va.z));
    cv[q3] = make_int2(ca.w, __float_as_int(va.w));
    cv[q4] = make_int2(cb.x, __float_as_int(vb.x));
    cv[q5] = make_int2(cb.y, __float_as_int(vb.y));
    cv[q6] = make_int2(cb.z, __float_as_int(vb.z));
    cv[q7] = make_int2(cb.w, __float_as_int(vb.w));
  } else {
    // ---- rel2: dense per-entity relation softmax table ----
    __shared__ __align__(16) float Vl[576];
    __shared__ float wsql[9];
    for (int i = threadIdx.x; i < 576; i += 256) Vl[i] = V[i];
    if (threadIdx.x < 9) wsql[threadIdx.x] = wsq[threadIdx.x];
    __syncthreads();
    int ent = (blockIdx.x - BUILD_BLOCKS) * 256 + threadIdx.x;
    if (ent >= N_ENT) return;
    float a[9] = {0, 0, 0, 0, 0, 0, 0, 0, 0};
    const uint4* row = (const uint4*)(ent0bf + (ent << 6));
#pragma unroll
    for (int q = 0; q < 8; ++q) {
      uint4 b = row[q];
      float ch0 = bf2f(b.x & 0xFFFFu), ch1 = bf2f(b.x >> 16);
      float ch2 = bf2f(b.y & 0xFFFFu), ch3 = bf2f(b.y >> 16);
      float ch4 = bf2f(b.z & 0xFFFFu), ch5 = bf2f(b.z >> 16);
      float ch6 = bf2f(b.w & 0xFFFFu), ch7 = bf2f(b.w >> 16);
#pragma unroll
      for (int r = 0; r < 9; ++r) {
        const float4* vp = (const float4*)(Vl + r * 64 + q * 8);
        float4 v0 = vp[0], v1 = vp[1];
        float t = a[r];
        t = fmaf(ch0, v0.x, t); t = fmaf(ch1, v0.y, t);
        t = fmaf(ch2, v0.z, t); t = fmaf(ch3, v0.w, t);
        t = fmaf(ch4, v1.x, t); t = fmaf(ch5, v1.y, t);
        t = fmaf(ch6, v1.z, t); t = fmaf(ch7, v1.w, t);
        a[r] = t;
      }
    }
    const float inv2s = 0.08838834764831845f;  // 1/(2*sqrt(32))
    int cnt[9];
#pragma unroll
    for (int r = 0; r < 9; ++r) cnt[r] = cnt9[ent * 9 + r];
    float m1 = -INFINITY;
#pragma unroll
    for (int r = 0; r < 9; ++r)
      if (cnt[r] > 0) m1 = fmaxf(m1, a[r] * inv2s);
    if (m1 == -INFINITY) {
#pragma unroll
      for (int r = 0; r < 9; ++r) rel2t[ent * 9 + r] = 0.f;
      return;
    }
    float den1 = 1e-16f;
#pragma unroll
    for (int r = 0; r < 9; ++r)
      if (cnt[r] > 0) den1 += (float)cnt[r] * expf(a[r] * inv2s - m1);
#pragma unroll
    for (int r = 0; r < 9; ++r) {
      float rs = expf(a[r] * inv2s - m1) / den1;
      rel2t[ent * 9 + r] = rs * rs * wsql[r];
    }
  }
}

// ---- KG aggregation from per-wave LDS row cache (rows written in group layout) ----
__device__ __forceinline__ float kg_agg_lds(int deg, int lane, int pk, float mk,
                                            const ushort_t* __restrict__ rc,
                                            const float* __restrict__ wl) {
  float a0 = 0.f, a1 = 0.f, a2 = 0.f, a3 = 0.f;
  int j = 0;
  for (; j + 4 <= deg; j += 4) {
    int p0 = rl(pk, j), p1 = rl(pk, j + 1), p2 = rl(pk, j + 2), p3 = rl(pk, j + 3);
    float k0 = rlf(mk, j), k1 = rlf(mk, j + 1), k2 = rlf(mk, j + 2), k3 = rlf(mk, j + 3);
    float r0 = bf2f(rc[((j + 0) << 6) + lane]);
    float r1 = bf2f(rc[((j + 1) << 6) + lane]);
    float r2 = bf2f(rc[((j + 2) << 6) + lane]);
    float r3 = bf2f(rc[((j + 3) << 6) + lane]);
    a0 = fmaf(r0 * wl[(((p0 >> 20) & 15) << 6) + lane], k0, a0);
    a1 = fmaf(r1 * wl[(((p1 >> 20) & 15) << 6) + lane], k1, a1);
    a2 = fmaf(r2 * wl[(((p2 >> 20) & 15) << 6) + lane], k2, a2);
    a3 = fmaf(r3 * wl[(((p3 >> 20) & 15) << 6) + lane], k3, a3);
  }
  for (; j < deg; ++j) {
    int pj = rl(pk, j);
    float kj = rlf(mk, j);
    a0 = fmaf(bf2f(rc[(j << 6) + lane]) * wl[(((pj >> 20) & 15) << 6) + lane], kj, a0);
  }
  return (a0 + a1) + (a2 + a3);
}

// KG aggregation inner (readlane broadcasts, 4 acc chains) — generic/global fallback
__device__ __forceinline__ float kg_agg64(int deg, int lane, int pk, float mk,
                                          const ushort_t* __restrict__ srcbf,
                                          const float* __restrict__ wl) {
  float a0 = 0.f, a1 = 0.f, a2 = 0.f, a3 = 0.f;
  int j = 0;
  for (; j + 4 <= deg; j += 4) {
    int p0 = rl(pk, j), p1 = rl(pk, j + 1), p2 = rl(pk, j + 2), p3 = rl(pk, j + 3);
    float k0 = rlf(mk, j), k1 = rlf(mk, j + 1), k2 = rlf(mk, j + 2), k3 = rlf(mk, j + 3);
    float r0 = bf2f(srcbf[((p0 & 0xFFFFF) << 6) + lane]);
    float r1 = bf2f(srcbf[((p1 & 0xFFFFF) << 6) + lane]);
    float r2 = bf2f(srcbf[((p2 & 0xFFFFF) << 6) + lane]);
    float r3 = bf2f(srcbf[((p3 & 0xFFFFF) << 6) + lane]);
    a0 = fmaf(r0 * wl[(((p0 >> 20) & 15) << 6) + lane], k0, a0);
    a1 = fmaf(r1 * wl[(((p1 >> 20) & 15) << 6) + lane], k1, a1);
    a2 = fmaf(r2 * wl[(((p2 >> 20) & 15) << 6) + lane], k2, a2);
    a3 = fmaf(r3 * wl[(((p3 >> 20) & 15) << 6) + lane], k3, a3);
  }
  for (; j < deg; ++j) {
    int pj = rl(pk, j);
    float kj = rlf(mk, j);
    a0 = fmaf(bf2f(srcbf[((pj & 0xFFFFF) << 6) + lane]) * wl[(((pj >> 20) & 15) << 6) + lane], kj, a0);
  }
  return (a0 + a1) + (a2 + a3);
}

// ---------------- UI aggregation body (group-load -> LDS cache -> per-lane agg) ----------------
__device__ __forceinline__ void ui_body(int usr, int lane,
                                        const ushort_t* __restrict__ srcbf,
                                        ushort_t* __restrict__ rcw,
                                        const float4* __restrict__ sc4,
                                        const float* __restrict__ addb,
                                        float* __restrict__ outp, float* __restrict__ nxt,
                                        const int* __restrict__ uptr,
                                        const int2* __restrict__ cv,
                                        const float* __restrict__ dwl,
                                        const float* __restrict__ latl,
                                        float4* __restrict__ sc4out) {
  float4 s4 = sc4[usr];
  float m = fmaxf(fmaxf(s4.x, s4.y), fmaxf(s4.z, s4.w));
  float e0 = expf(s4.x - m), e1 = expf(s4.y - m), e2 = expf(s4.z - m), e3 = expf(s4.w - m);
  float den = e0 + e1 + e2 + e3;
  float mix = (e0 * dwl[lane] + e1 * dwl[64 + lane] + e2 * dwl[128 + lane] + e3 * dwl[192 + lane]) / den;
  int s = uptr[usr], e = uptr[usr + 1];
  int g = lane >> 3, part = lane & 7;
  float a0 = 0.f, a1 = 0.f, a2 = 0.f, a3 = 0.f;
  for (int base = s; base < e; base += 64) {
    int c = min(64, e - base);
    int2 cvl = (lane < c) ? cv[base + lane] : make_int2(0, 0);
    int cl = cvl.x;
    float vl = __int_as_float(cvl.y);
    int nch = (c + 7) >> 3;
    uint4 buf[8];
#pragma unroll
    for (int c2 = 0; c2 < 8; ++c2) {
      if (c2 < nch) {
        int cj = __shfl(cl, (c2 << 3) + g);
        buf[c2] = *((const uint4*)(srcbf + ((size_t)cj << 6)) + part);
      }
    }
#pragma unroll
    for (int c2 = 0; c2 < 8; ++c2) {
      if (c2 < nch) *(uint4*)&rcw[(((c2 << 3) + g) << 6) + (part << 3)] = buf[c2];
    }
    int j = 0;
    for (; j + 8 <= c; j += 8) {
      float v0 = rlf(vl, j), v1 = rlf(vl, j + 1), v2 = rlf(vl, j + 2), v3 = rlf(vl, j + 3);
      float v4 = rlf(vl, j + 4), v5 = rlf(vl, j + 5), v6 = rlf(vl, j + 6), v7 = rlf(vl, j + 7);
      float r0 = bf2f(rcw[((j + 0) << 6) + lane]);
      float r1 = bf2f(rcw[((j + 1) << 6) + lane]);
      float r2 = bf2f(rcw[((j + 2) << 6) + lane]);
      float r3 = bf2f(rcw[((j + 3) << 6) + lane]);
      float r4 = bf2f(rcw[((j + 4) << 6) + lane]);
      float r5 = bf2f(rcw[((j + 5) << 6) + lane]);
      float r6 = bf2f(rcw[((j + 6) << 6) + lane]);
      float r7 = bf2f(rcw[((j + 7) << 6) + lane]);
      a0 = fmaf(r0, v0, a0); a1 = fmaf(r1, v1, a1);
      a2 = fmaf(r2, v2, a2); a3 = fmaf(r3, v3, a3);
      a0 = fmaf(r4, v4, a0); a1 = fmaf(r5, v5, a1);
      a2 = fmaf(r6, v6, a2); a3 = fmaf(r7, v7, a3);
    }
    for (; j < c; ++j) {
      float vj = rlf(vl, j);
      a0 = fmaf(bf2f(rcw[(j << 6) + lane]), vj, a0);
    }
  }
  float acc = (a0 + a1) + (a2 + a3);
  float ua = acc * mix + acc;
  float nrm = sqrtf(waveReduceSum(ua * ua));
  float val = ua / fmaxf(nrm, 1e-12f);
  size_t o = (size_t)usr * 64 + lane;
  if (nxt) nxt[o] = val;
  outp[o] = addb[o] + val;
  if (sc4out) {
    // fused hop-2 factor scores: sc4b[usr] = val @ latent^T
    float s0 = waveReduceSum(val * latl[lane]);
    float s1 = waveReduceSum(val * latl[64 + lane]);
    float s2 = waveReduceSum(val * latl[128 + lane]);
    float s3 = waveReduceSum(val * latl[192 + lane]);
    if (lane == 0) sc4out[usr] = make_float4(s0, s1, s2, s3);
  }
}

// ---------------- D1: mask + fused KG hop-1  |  UI hop-1 (+sc4b) ----------------
__global__ void k_mask_kg_ui(const float* __restrict__ ent0,
                             const ushort_t* __restrict__ ent0bf,
                             const int* __restrict__ hptr, const int* __restrict__ packed,
                             const float* __restrict__ rel2t,
                             float* __restrict__ mask_s, const float* __restrict__ weight,
                             float* __restrict__ out_ent, ushort_t* __restrict__ ent1bf,
                             const float4* __restrict__ sc4,
                             float* __restrict__ out_usr,
                             float* __restrict__ usr1, const int* __restrict__ uptr,
                             const int2* __restrict__ cv,
                             const float* __restrict__ user_emb, const float* __restrict__ dw,
                             const float* __restrict__ latent, float4* __restrict__ sc4b) {
  // per-wave row cache: 64 rows x 64 bf16 (8 KB/wave). Broadcast reads are
  // 2-way bank aliased (free); b128 group writes hit the structural 8-phase floor.
  __shared__ __align__(16) ushort_t rc[4][64][64];
  int lane = threadIdx.x & 63, wid = threadIdx.x >> 6;
  ushort_t* rcw = &rc[wid][0][0];
  if (blockIdx.x < KG_BLOCKS) {
    __shared__ __align__(16) float sh_eh[4][64];
    __shared__ float wl[576];
    for (int i = threadIdx.x; i < 576; i += 256) wl[i] = weight[i];
    int ent = blockIdx.x * 4 + wid;  // always < N_ENT
    int s = hptr[ent], e = hptr[ent + 1];
    float eh = ent0[(size_t)ent * 64 + lane];
    sh_eh[wid][lane] = eh;
    __syncthreads();
    size_t o = (size_t)ent * 64 + lane;
    int deg = e - s;
    if (deg == 0) {
      ent1bf[o] = f2bf(0.f);
      out_ent[o] = eh;
      return;
    }
    if (deg <= 64) {
      // ---- hot path: one pass over rows; cache rows in LDS during dot ----
      int pk = (lane < deg) ? packed[s + lane] : 0;
      int tb = (pk >> 20) & 15;
      float r2sel = rel2t[ent * 9 + ((lane < deg) ? tb : 0)];
      int g = lane >> 3, part = lane & 7;
      const float4* ehq = (const float4*)(sh_eh[wid] + (part << 3));
      float4 ef0 = ehq[0], ef1 = ehq[1];
      int nch = (deg + 7) >> 3;
      // issue ALL chunk loads up-front (up to 8 x 1KB in flight)
      uint4 buf[8];
#pragma unroll
      for (int c2 = 0; c2 < 8; ++c2) {
        if (c2 < nch) {
          int pkj = __shfl(pk, (c2 << 3) + g);
          buf[c2] = *((const uint4*)(ent0bf + ((size_t)(pkj & 0xFFFFF) << 6)) + part);
        }
      }
      float myDot = 0.f;
#pragma unroll
      for (int c2 = 0; c2 < 8; ++c2) {
        if (c2 < nch) {
          uint4 b = buf[c2];
          *(uint4*)&rcw[(((c2 << 3) + g) << 6) + (part << 3)] = b;
          float s0 = bf2f(b.x & 0xFFFFu) * ef0.x;
          float s1 = bf2f(b.y & 0xFFFFu) * ef0.z;
          float s2 = bf2f(b.z & 0xFFFFu) * ef1.x;
          float s3 = bf2f(b.w & 0xFFFFu) * ef1.z;
          s0 = fmaf(bf2f(b.x >> 16), ef0.y, s0);
          s1 = fmaf(bf2f(b.y >> 16), ef0.w, s1);
          s2 = fmaf(bf2f(b.z >> 16), ef1.y, s2);
          s3 = fmaf(bf2f(b.w >> 16), ef1.w, s3);
          float sv = (s0 + s1) + (s2 + s3);
          sv += __shfl_xor(sv, 1);
          sv += __shfl_xor(sv, 2);
          sv += __shfl_xor(sv, 4);
          float got = __shfl(sv, part << 3);
          myDot = ((lane >> 3) == c2) ? got : myDot;
        }
      }
      float trip = (lane < deg) ? myDot + r2sel : -INFINITY;
      float m2 = waveReduceMax(trip);
      float ex = (lane < deg) ? expf(trip - m2) : 0.f;
      float den2 = waveReduceSum(ex) + 1e-16f;
      float mk = ex / den2;
      if (lane < deg) mask_s[s + lane] = mk;
      // ---- fused KG hop-1 aggregation from the LDS row cache ----
      float acc = kg_agg_lds(deg, lane, pk, mk, rcw, wl);
      float agg = acc / (float)deg;
      float nrm = sqrtf(waveReduceSum(agg * agg));
      float val = agg / fmaxf(nrm, 1e-12f);
      ent1bf[o] = f2bf(val);
      out_ent[o] = eh + val;
    } else {
      // ---- generic multi-chunk path ----
      float m2l = -INFINITY;
      for (int base = s; base < e; base += 64) {
        int c = min(64, e - base);
        int pk = (lane < c) ? packed[base + lane] : 0;
        int tb = (pk >> 20) & 15;
        float r2 = rel2t[ent * 9 + ((lane < c) ? tb : 0)];
        int tl = pk & 0xFFFFF;
        const uint4* row = (const uint4*)(ent0bf + (tl << 6));
        const float* ehp = sh_eh[wid];
        float d = 0.f;
#pragma unroll
        for (int q = 0; q < 8; ++q) {
          uint4 a = row[q];
          d += bf2f(a.x & 0xFFFF) * ehp[q * 8 + 0] + bf2f(a.x >> 16) * ehp[q * 8 + 1];
          d += bf2f(a.y & 0xFFFF) * ehp[q * 8 + 2] + bf2f(a.y >> 16) * ehp[q * 8 + 3];
          d += bf2f(a.z & 0xFFFF) * ehp[q * 8 + 4] + bf2f(a.z >> 16) * ehp[q * 8 + 5];
          d += bf2f(a.w & 0xFFFF) * ehp[q * 8 + 6] + bf2f(a.w >> 16) * ehp[q * 8 + 7];
        }
        float trip = d + r2;
        if (lane < c) {
          mask_s[base + lane] = trip;
          m2l = fmaxf(m2l, trip);
        }
      }
      float m2 = waveReduceMax(m2l);
      float denl = 0.f;
      for (int base = s; base < e; base += 64) {
        int c = min(64, e - base);
        denl += (lane < c) ? expf(mask_s[base + lane] - m2) : 0.f;
      }
      float den2 = waveReduceSum(denl) + 1e-16f;
      float acc = 0.f;
      for (int base = s; base < e; base += 64) {
        int c = min(64, e - base);
        int pk = (lane < c) ? packed[base + lane] : 0;
        float mk = 0.f;
        if (lane < c) {
          mk = expf(mask_s[base + lane] - m2) / den2;
          mask_s[base + lane] = mk;
        }
        acc += kg_agg64(c, lane, pk, mk, ent0bf, wl);
      }
      float agg = acc / (float)deg;
      float nrm = sqrtf(waveReduceSum(agg * agg));
      float val = agg / fmaxf(nrm, 1e-12f);
      ent1bf[o] = f2bf(val);
      out_ent[o] = eh + val;
    }
  } else {
    __shared__ float dwl[256];
    __shared__ float latl[256];
    if (threadIdx.x < 256) {
      dwl[threadIdx.x] = dw[threadIdx.x];
      latl[threadIdx.x] = latent[threadIdx.x];
    }
    __syncthreads();
    int usr = (blockIdx.x - KG_BLOCKS) * 4 + wid;  // always < N_USR
    ui_body(usr, lane, ent0bf, rcw, sc4, user_emb, out_usr, usr1,
            uptr, cv, dwl, latl, sc4b);
  }
}

// ---------------- D2: KG hop-2 + UI hop-2 ----------------
__global__ void k_hop2(const ushort_t* __restrict__ srcbf,
                       float* __restrict__ out_ent,
                       const int* __restrict__ hptr, const int* __restrict__ packed,
                       const float* __restrict__ mask_s, const float* __restrict__ weight,
                       const float* __restrict__ usr1, float* __restrict__ out_usr,
                       const int* __restrict__ uptr, const int2* __restrict__ cv,
                       const float4* __restrict__ sc4,
                       const float* __restrict__ dw) {
  __shared__ __align__(16) ushort_t rc[4][64][64];
  int lane = threadIdx.x & 63, wid = threadIdx.x >> 6;
  ushort_t* rcw = &rc[wid][0][0];
  if (blockIdx.x < KG_BLOCKS) {
    __shared__ float wl[576];
    for (int i = threadIdx.x; i < 576; i += 256) wl[i] = weight[i];
    __syncthreads();
    int ent = blockIdx.x * 4 + wid;
    int s = hptr[ent], e = hptr[ent + 1];
    int g = lane >> 3, part = lane & 7;
    float acc = 0.f;
    for (int base = s; base < e; base += 64) {
      int c = min(64, e - base);
      int pk = (lane < c) ? packed[base + lane] : 0;
      float mk = (lane < c) ? mask_s[base + lane] : 0.f;
      int nch = (c + 7) >> 3;
      uint4 buf[8];
#pragma unroll
      for (int c2 = 0; c2 < 8; ++c2) {
        if (c2 < nch) {
          int pkj = __shfl(pk, (c2 << 3) + g);
          buf[c2] = *((const uint4*)(srcbf + ((size_t)(pkj & 0xFFFFF) << 6)) + part);
        }
      }
#pragma unroll
      for (int c2 = 0; c2 < 8; ++c2) {
        if (c2 < nch) *(uint4*)&rcw[(((c2 << 3) + g) << 6) + (part << 3)] = buf[c2];
      }
      acc += kg_agg_lds(c, lane, pk, mk, rcw, wl);
    }
    float n = (float)(e - s);
    float agg = acc / fmaxf(n, 1.0f);
    float nrm = sqrtf(waveReduceSum(agg * agg));
    float val = agg / fmaxf(nrm, 1e-12f);
    size_t o = (size_t)ent * 64 + lane;
    out_ent[o] = out_ent[o] + val;
  } else {
    __shared__ float dwl[256];
    if (threadIdx.x < 256) dwl[threadIdx.x] = dw[threadIdx.x];
    __syncthreads();
    int usr = (blockIdx.x - KG_BLOCKS) * 4 + wid;
    ui_body(usr, lane, srcbf, rcw, sc4, out_usr, out_usr, nullptr,
            uptr, cv, dwl, nullptr, nullptr);
  }
}

extern "C" void kernel_launch(void* const* d_in, const int* in_sizes, int n_in,
                              void* d_out, int out_size, void* d_ws, size_t ws_size,
                              hipStream_t stream) {
  const float* user_emb = (const float*)d_in[0];
  const float* entity_emb = (const float*)d_in[1];
  const float* latent = (const float*)d_in[2];
  const float* weight = (const float*)d_in[3];
  const float* disen = (const float*)d_in[4];
  const float* kgW = (const float*)d_in[5];
  const float* ui_vals = (const float*)d_in[6];
  const int* edge_index = (const int*)d_in[7];
  const int* edge_type = (const int*)d_in[8];
  const int* ui_rows = (const int*)d_in[9];
  const int* ui_cols = (const int*)d_in[10];
  const int* head = edge_index;
  const int* tail = edge_index + N_EDGE;

  char* ws = (char*)d_ws;
  size_t o = 0;
  auto alloc = [&](size_t bytes) -> char* {
    char* p = ws + o;
    o += (bytes + 255) & ~(size_t)255;
    return p;
  };
  int* head_ptr = (int*)alloc((N_ENT + 1) * 4);
  int* head_cur = (int*)alloc((size_t)N_ENT * 4);
  int* ui_ptr = (int*)alloc((N_USR + 1) * 4);
  int* ui_cur = (int*)alloc((size_t)N_USR * 4);
  int* bsum_h = (int*)alloc(256 * 4);
  int* bsum_u = (int*)alloc(256 * 4);
  int* packed = (int*)alloc((size_t)N_EDGE * 4);
  int2* cv = (int2*)alloc((size_t)N_EDGE * 8);
  float* mask_s = (float*)alloc((size_t)N_EDGE * 4);
  ushort_t* ent0bf = (ushort_t*)alloc((size_t)N_ENT * 64 * 2);
  ushort_t* ent1bf = (ushort_t*)alloc((size_t)N_ENT * 64 * 2);
  float* usr1 = (float*)alloc((size_t)N_USR * 64 * 4);
  int* cnt9 = (int*)alloc((size_t)N_ENT * 9 * 4);
  float* rel2t = (float*)alloc((size_t)N_ENT * 9 * 4);
  float4* sc4a = (float4*)alloc((size_t)N_USR * 16);
  float4* sc4b = (float4*)alloc((size_t)N_USR * 16);
  float* V = (float*)alloc(9 * 64 * 4);
  float* wsq = (float*)alloc(16 * 4);
  float* dw = (float*)alloc(4 * 64 * 4);
  if (o > ws_size) return;

  float* out_ent = (float*)d_out;
  float* out_usr = out_ent + (size_t)N_ENT * 64;
  float* out_cor = out_ent + (size_t)N_ENT * 64 + (size_t)N_USR * 64;

  hipMemsetAsync(ui_cur, 0, (size_t)N_USR * 4, stream);
  hipMemsetAsync(cnt9, 0, (size_t)N_ENT * 9 * 4, stream);

  // K1: bf16 convert + count + prep + sc(user)
  k_pre<<<TB_BLOCKS + CNT_BLOCKS + 1 + SC_BLOCKS, 256, 0, stream>>>(
      entity_emb, ent0bf, head, ui_rows, edge_type, ui_cur, cnt9,
      weight, kgW, disen, V, wsq, dw, out_cor, user_emb, latent, sc4a);

  int nbh = (N_ENT + 1023) / 1024, nbu = (N_USR + 1023) / 1024;
  // K2: fused scan-reduce
  k_scanred<<<nbh + nbu, 256, 0, stream>>>(cnt9, ui_cur, bsum_h, bsum_u, nbh);
  // K3: block-sum exclusive scans
  k_scan_tops<<<1, 64, 0, stream>>>(bsum_h, nbh, bsum_u, nbu, head_ptr, N_ENT, ui_ptr, N_USR, N_EDGE);
  // K4: fused scan-final
  k_scanfin<<<nbh + nbu, 256, 0, stream>>>(cnt9, bsum_h, bsum_u,
                                           head_ptr, head_cur, ui_ptr, ui_cur, nbh);
  // K5: build + rel2
  k_build_rel2<<<BUILD_BLOCKS + REL2_BLOCKS, 256, 0, stream>>>(
      head, tail, edge_type, ui_rows, ui_cols, ui_vals,
      head_cur, ui_cur, packed, cv, ent0bf, V, wsq, cnt9, rel2t);

  // D1: mask + fused KG hop-1 + UI hop-1 (+ sc4b epilogue)
  k_mask_kg_ui<<<KG_BLOCKS + UI_BLOCKS, 256, 0, stream>>>(
      entity_emb, ent0bf, head_ptr, packed, rel2t, mask_s, weight,
      out_ent, ent1bf, sc4a, out_usr, usr1, ui_ptr, cv, user_emb, dw, latent, sc4b);

  // D2: KG hop-2 + UI hop-2
  k_hop2<<<KG_BLOCKS + UI_BLOCKS, 256, 0, stream>>>(
      ent1bf, out_ent, head_ptr, packed, mask_s, weight,
      usr1, out_usr, ui_ptr, cv, sc4b, dw);
}

// Round 2
// 595.405 us; speedup vs baseline: 1.2286x; 1.2286x over previous
//
#include <hip/hip_runtime.h>
#include <math.h>

#define N_ENT 100000
#define N_USR 50000
#define N_EDGE 1000000
#define TEMPC 0.2f
#define KG_BLOCKS (N_ENT / 4)   // 25000, exact
#define UI_BLOCKS (N_USR / 4)   // 12500, exact

// fused-kernel block ranges
#define TB_BLOCKS 6250   // ceil(N_ENT*64/4 / 256) : bf16 convert (float4 granules)
#define CNT_BLOCKS 489   // ceil(N_EDGE/8 / 256) : count, 8 edges/thread
#define SC_BLOCKS 196    // ceil(N_USR / 256)
#define BUILD_BLOCKS 489 // ceil(N_EDGE/8 / 256)
#define REL2_BLOCKS 391  // ceil(N_ENT / 256)

typedef unsigned short ushort_t;

__device__ __forceinline__ float waveReduceSum(float x) {
#pragma unroll
  for (int d = 32; d > 0; d >>= 1) x += __shfl_xor(x, d);
  return x;
}
__device__ __forceinline__ float waveReduceMax(float x) {
#pragma unroll
  for (int d = 32; d > 0; d >>= 1) x = fmaxf(x, __shfl_xor(x, d));
  return x;
}
__device__ __forceinline__ int waveReduceSumI(int x) {
#pragma unroll
  for (int d = 32; d > 0; d >>= 1) x += __shfl_xor(x, d);
  return x;
}
__device__ __forceinline__ float bf2f(unsigned int u16) {
  union { unsigned int i; float f; } v;
  v.i = u16 << 16;
  return v.f;
}
__device__ __forceinline__ ushort_t f2bf(float f) {
  union { unsigned int i; float f; } v;
  v.f = f;
  unsigned int u = v.i;
  u = (u + 0x7FFFu + ((u >> 16) & 1u)) >> 16;
  return (ushort_t)u;
}
// wave-uniform broadcast via v_readlane -> SGPR (cheap scalar addressing downstream)
__device__ __forceinline__ int rl(int v, int l) { return __builtin_amdgcn_readlane(v, l); }
__device__ __forceinline__ float rlf(float v, int l) {
  return __int_as_float(__builtin_amdgcn_readlane(__float_as_int(v), l));
}

// ============ K1: bf16 convert | edge count (8/thr) | prep | sc(user) ============
__global__ void k_pre(const float* __restrict__ ent0, ushort_t* __restrict__ ent0bf,
                      const int* __restrict__ head, const int* __restrict__ uir,
                      const int* __restrict__ etype,
                      int* __restrict__ cnt_u, int* __restrict__ cnt9,
                      const float* __restrict__ weight, const float* __restrict__ kgW,
                      const float* __restrict__ disen,
                      float* __restrict__ V, float* __restrict__ wsq,
                      float* __restrict__ dw, float* __restrict__ cor_out,
                      const float* __restrict__ user_emb, const float* __restrict__ latent,
                      float4* __restrict__ sc4a) {
  int bid = blockIdx.x;
  if (bid < TB_BLOCKS) {
    int i = bid * 256 + threadIdx.x;
    if (i < N_ENT * 16) {
      float4 v = ((const float4*)ent0)[i];
      ushort4 o;
      o.x = f2bf(v.x); o.y = f2bf(v.y); o.z = f2bf(v.z); o.w = f2bf(v.w);
      ((ushort4*)ent0bf)[i] = o;
    }
  } else if (bid < TB_BLOCKS + CNT_BLOCKS) {
    int i0 = ((bid - TB_BLOCKS) * 256 + threadIdx.x) * 8;
    if (i0 < N_EDGE) {
      int4 ha = *(const int4*)(head + i0), hb = *(const int4*)(head + i0 + 4);
      int4 ea = *(const int4*)(etype + i0), eb = *(const int4*)(etype + i0 + 4);
      int4 ua = *(const int4*)(uir + i0), ub = *(const int4*)(uir + i0 + 4);
      atomicAdd(&cnt9[ha.x * 9 + (ea.x - 1)], 1);
      atomicAdd(&cnt9[ha.y * 9 + (ea.y - 1)], 1);
      atomicAdd(&cnt9[ha.z * 9 + (ea.z - 1)], 1);
      atomicAdd(&cnt9[ha.w * 9 + (ea.w - 1)], 1);
      atomicAdd(&cnt9[hb.x * 9 + (eb.x - 1)], 1);
      atomicAdd(&cnt9[hb.y * 9 + (eb.y - 1)], 1);
      atomicAdd(&cnt9[hb.z * 9 + (eb.z - 1)], 1);
      atomicAdd(&cnt9[hb.w * 9 + (eb.w - 1)], 1);
      atomicAdd(&cnt_u[ua.x], 1);
      atomicAdd(&cnt_u[ua.y], 1);
      atomicAdd(&cnt_u[ua.z], 1);
      atomicAdd(&cnt_u[ua.w], 1);
      atomicAdd(&cnt_u[ub.x], 1);
      atomicAdd(&cnt_u[ub.y], 1);
      atomicAdd(&cnt_u[ub.z], 1);
      atomicAdd(&cnt_u[ub.w], 1);
    }
  } else if (bid == TB_BLOCKS + CNT_BLOCKS) {
    // ---- prep: V=(W W^T)w_r via T-factorization, wsq, dw, cor ----
    __shared__ float T[9 * 64];
    __shared__ float sm[4 * 9];
    int tid = threadIdx.x;
    for (int e = tid; e < 9 * 64; e += 256) {
      int r = e >> 6, d = e & 63;
      float s = 0.f;
      for (int k = 0; k < 64; ++k) s += kgW[k * 64 + d] * weight[r * 64 + k];
      T[e] = s;
    }
    if (tid < 4) {
      float m = -INFINITY;
      for (int r = 0; r < 9; ++r) m = fmaxf(m, disen[tid * 9 + r]);
      float den = 0.f;
      float ex[9];
      for (int r = 0; r < 9; ++r) { ex[r] = expf(disen[tid * 9 + r] - m); den += ex[r]; }
      for (int r = 0; r < 9; ++r) sm[tid * 9 + r] = ex[r] / den;
    }
    __syncthreads();
    for (int e = tid; e < 9 * 64; e += 256) {
      int r = e >> 6, i = e & 63;
      float s = 0.f;
      for (int d = 0; d < 64; ++d) s += kgW[i * 64 + d] * T[r * 64 + d];
      V[e] = s;
    }
    if (tid < 9) {
      float s = 0.f;
      for (int c = 0; c < 64; ++c) { float w = weight[tid * 64 + c]; s += w * w; }
      wsq[tid] = s;
    }
    for (int e = tid; e < 4 * 64; e += 256) {
      int f = e >> 6, c = e & 63;
      float s = 0.f;
      for (int r = 0; r < 9; ++r) s += sm[f * 9 + r] * weight[r * 64 + c];
      dw[e] = s;
    }
    if (tid == 0) {
      float rowsum[4];
      for (int f = 0; f < 4; ++f) {
        float s = 0.f;
        for (int j = 0; j < 9; ++j) s += disen[f * 9 + j];
        rowsum[f] = s;
      }
      float cor = 0.f;
      for (int i = 0; i < 9; ++i) {
        float n2 = 0.f, ttl = 0.f;
        for (int f = 0; f < 4; ++f) {
          float v = disen[f * 9 + i];
          n2 += v * v;
          ttl += v * rowsum[f];
        }
        float nrm = sqrtf(n2);
        float pos = 0.f;
        for (int f = 0; f < 4; ++f) {
          float v = disen[f * 9 + i] / nrm;
          pos += v * v;
        }
        cor += (ttl - pos) / TEMPC;
      }
      *cor_out = cor;
    }
  } else {
    // ---- sc on user_emb -> sc4a ----
    __shared__ __align__(16) float lat[256];
    if (threadIdx.x < 256) lat[threadIdx.x] = latent[threadIdx.x];
    __syncthreads();
    int u = (bid - TB_BLOCKS - CNT_BLOCKS - 1) * 256 + threadIdx.x;
    if (u >= N_USR) return;
    float a0 = 0.f, a1 = 0.f, a2 = 0.f, a3 = 0.f;
    const float4* row = (const float4*)(user_emb + (size_t)u * 64);
#pragma unroll
    for (int q = 0; q < 16; ++q) {
      float4 v = row[q];
      float4 l0 = *(const float4*)(lat + 0 * 64 + q * 4);
      float4 l1 = *(const float4*)(lat + 1 * 64 + q * 4);
      float4 l2 = *(const float4*)(lat + 2 * 64 + q * 4);
      float4 l3 = *(const float4*)(lat + 3 * 64 + q * 4);
      a0 = fmaf(v.x, l0.x, a0); a0 = fmaf(v.y, l0.y, a0); a0 = fmaf(v.z, l0.z, a0); a0 = fmaf(v.w, l0.w, a0);
      a1 = fmaf(v.x, l1.x, a1); a1 = fmaf(v.y, l1.y, a1); a1 = fmaf(v.z, l1.z, a1); a1 = fmaf(v.w, l1.w, a1);
      a2 = fmaf(v.x, l2.x, a2); a2 = fmaf(v.y, l2.y, a2); a2 = fmaf(v.z, l2.z, a2); a2 = fmaf(v.w, l2.w, a2);
      a3 = fmaf(v.x, l3.x, a3); a3 = fmaf(v.y, l3.y, a3); a3 = fmaf(v.z, l3.z, a3); a3 = fmaf(v.w, l3.w, a3);
    }
    sc4a[u] = make_float4(a0, a1, a2, a3);
  }
}

// ============ K2: fused scan-reduce (head from cnt9 rowsums | ui) ============
__global__ void k_scanred(const int* __restrict__ cnt9, const int* __restrict__ cnt_u,
                          int* __restrict__ bsum_h, int* __restrict__ bsum_u, int nbh) {
  int b = blockIdx.x, tid = threadIdx.x;
  int s = 0;
  if (b < nbh) {
    int i0 = b * 1024 + tid * 4;
#pragma unroll
    for (int k = 0; k < 4; ++k)
      if (i0 + k < N_ENT) {
        int base = (i0 + k) * 9;
#pragma unroll
        for (int r = 0; r < 9; ++r) s += cnt9[base + r];
      }
  } else {
    int i0 = (b - nbh) * 1024 + tid * 4;
#pragma unroll
    for (int k = 0; k < 4; ++k)
      if (i0 + k < N_USR) s += cnt_u[i0 + k];
  }
  s = waveReduceSumI(s);
  __shared__ int l[4];
  int lane = tid & 63, wid = tid >> 6;
  if (lane == 0) l[wid] = s;
  __syncthreads();
  if (tid == 0) {
    int v = l[0] + l[1] + l[2] + l[3];
    if (b < nbh) bsum_h[b] = v; else bsum_u[b - nbh] = v;
  }
}

__global__ void k_scan_tops(int* bsA, int nA, int* bsB, int nB,
                            int* ptrA, int NA, int* ptrB, int NB, int total) {
  if (threadIdx.x == 0) {
    int a = 0;
    for (int i = 0; i < nA; ++i) { int t = bsA[i]; bsA[i] = a; a += t; }
    ptrA[NA] = total;
  }
  if (threadIdx.x == 1) {
    int a = 0;
    for (int i = 0; i < nB; ++i) { int t = bsB[i]; bsB[i] = a; a += t; }
    ptrB[NB] = total;
  }
}

// ============ K4: fused scan-final (head from cnt9 | ui) ============
__global__ void k_scanfin(const int* __restrict__ cnt9, const int* __restrict__ bsum_h,
                          const int* __restrict__ bsum_u,
                          int* __restrict__ head_ptr, int* __restrict__ head_cur,
                          int* __restrict__ ui_ptr, int* __restrict__ ui_cur, int nbh) {
  int b = blockIdx.x, tid = threadIdx.x;
  bool isH = (b < nbh);
  int bl = isH ? b : b - nbh;
  int n = isH ? N_ENT : N_USR;
  int i0 = bl * 1024 + tid * 4;
  int c[4];
  int s = 0;
  int loc[4];
#pragma unroll
  for (int k = 0; k < 4; ++k) {
    int v = 0;
    if (i0 + k < n) {
      if (isH) {
        int base = (i0 + k) * 9;
#pragma unroll
        for (int r = 0; r < 9; ++r) v += cnt9[base + r];
      } else {
        v = ui_cur[i0 + k];
      }
    }
    c[k] = v;
    loc[k] = s;
    s += v;
  }
  int lane = tid & 63, wid = tid >> 6;
  int x = s;
#pragma unroll
  for (int d = 1; d < 64; d <<= 1) {
    int y = __shfl_up(x, d);
    if (lane >= d) x += y;
  }
  __shared__ int l[4];
  if (lane == 63) l[wid] = x;
  __syncthreads();
  if (tid == 0) {
    int a = 0;
    for (int w = 0; w < 4; ++w) { int t = l[w]; l[w] = a; a += t; }
  }
  __syncthreads();
  int excl = x - s + l[wid] + (isH ? bsum_h[bl] : bsum_u[bl]);
#pragma unroll
  for (int k = 0; k < 4; ++k) {
    if (i0 + k < n) {
      int v = excl + loc[k];
      if (isH) {
        head_ptr[i0 + k] = v;
        head_cur[i0 + k] = v;
      } else {
        ui_ptr[i0 + k] = v;
        ui_cur[i0 + k] = v;
      }
    }
  }
}

// ============ K5: build (8/thr) | rel2 ============
__global__ void k_build_rel2(const int* __restrict__ head, const int* __restrict__ tail,
                             const int* __restrict__ etype,
                             const int* __restrict__ uir, const int* __restrict__ uic,
                             const float* __restrict__ uival,
                             int* __restrict__ cur_h, int* __restrict__ cur_u,
                             int* __restrict__ packed, int2* __restrict__ cv,
                             const ushort_t* __restrict__ ent0bf, const float* __restrict__ V,
                             const float* __restrict__ wsq, const int* __restrict__ cnt9,
                             float* __restrict__ rel2t) {
  if (blockIdx.x < BUILD_BLOCKS) {
    int i0 = (blockIdx.x * 256 + threadIdx.x) * 8;
    if (i0 >= N_EDGE) return;
    int4 ha = *(const int4*)(head + i0), hb = *(const int4*)(head + i0 + 4);
    int4 ta = *(const int4*)(tail + i0), tb4 = *(const int4*)(tail + i0 + 4);
    int4 ea = *(const int4*)(etype + i0), eb = *(const int4*)(etype + i0 + 4);
    int4 ua = *(const int4*)(uir + i0), ub = *(const int4*)(uir + i0 + 4);
    int4 ca = *(const int4*)(uic + i0), cb = *(const int4*)(uic + i0 + 4);
    float4 va = *(const float4*)(uival + i0), vb = *(const float4*)(uival + i0 + 4);
    int p0 = atomicAdd(&cur_h[ha.x], 1);
    int p1 = atomicAdd(&cur_h[ha.y], 1);
    int p2 = atomicAdd(&cur_h[ha.z], 1);
    int p3 = atomicAdd(&cur_h[ha.w], 1);
    int p4 = atomicAdd(&cur_h[hb.x], 1);
    int p5 = atomicAdd(&cur_h[hb.y], 1);
    int p6 = atomicAdd(&cur_h[hb.z], 1);
    int p7 = atomicAdd(&cur_h[hb.w], 1);
    int q0 = atomicAdd(&cur_u[ua.x], 1);
    int q1 = atomicAdd(&cur_u[ua.y], 1);
    int q2 = atomicAdd(&cur_u[ua.z], 1);
    int q3 = atomicAdd(&cur_u[ua.w], 1);
    int q4 = atomicAdd(&cur_u[ub.x], 1);
    int q5 = atomicAdd(&cur_u[ub.y], 1);
    int q6 = atomicAdd(&cur_u[ub.z], 1);
    int q7 = atomicAdd(&cur_u[ub.w], 1);
    packed[p0] = (ta.x & 0xFFFFF) | ((ea.x - 1) << 20);
    packed[p1] = (ta.y & 0xFFFFF) | ((ea.y - 1) << 20);
    packed[p2] = (ta.z & 0xFFFFF) | ((ea.z - 1) << 20);
    packed[p3] = (ta.w & 0xFFFFF) | ((ea.w - 1) << 20);
    packed[p4] = (tb4.x & 0xFFFFF) | ((eb.x - 1) << 20);
    packed[p5] = (tb4.y & 0xFFFFF) | ((eb.y - 1) << 20);
    packed[p6] = (tb4.z & 0xFFFFF) | ((eb.z - 1) << 20);
    packed[p7] = (tb4.w & 0xFFFFF) | ((eb.w - 1) << 20);
    cv[q0] = make_int2(ca.x, __float_as_int(va.x));
    cv[q1] = make_int2(ca.y, __float_as_int(va.y));
    cv[q2] = make_int2(ca.z, __float_as_int(va.z));
    cv[q3] = make_int2(ca.w, __float_as_int(va.w));
    cv[q4] = make_int2(cb.x, __float_as_int(vb.x));
    cv[q5] = make_int2(cb.y, __float_as_int(vb.y));
    cv[q6] = make_int2(cb.z, __float_as_int(vb.z));
    cv[q7] = make_int2(cb.w, __float_as_int(vb.w));
  } else {
    // ---- rel2: dense per-entity relation softmax table ----
    __shared__ __align__(16) float Vl[576];
    __shared__ float wsql[9];
    for (int i = threadIdx.x; i < 576; i += 256) Vl[i] = V[i];
    if (threadIdx.x < 9) wsql[threadIdx.x] = wsq[threadIdx.x];
    __syncthreads();
    int ent = (blockIdx.x - BUILD_BLOCKS) * 256 + threadIdx.x;
    if (ent >= N_ENT) return;
    float a[9] = {0, 0, 0, 0, 0, 0, 0, 0, 0};
    const uint4* row = (const uint4*)(ent0bf + (ent << 6));
#pragma unroll
    for (int q = 0; q < 8; ++q) {
      uint4 b = row[q];
      float ch0 = bf2f(b.x & 0xFFFFu), ch1 = bf2f(b.x >> 16);
      float ch2 = bf2f(b.y & 0xFFFFu), ch3 = bf2f(b.y >> 16);
      float ch4 = bf2f(b.z & 0xFFFFu), ch5 = bf2f(b.z >> 16);
      float ch6 = bf2f(b.w & 0xFFFFu), ch7 = bf2f(b.w >> 16);
#pragma unroll
      for (int r = 0; r < 9; ++r) {
        const float4* vp = (const float4*)(Vl + r * 64 + q * 8);
        float4 v0 = vp[0], v1 = vp[1];
        float t = a[r];
        t = fmaf(ch0, v0.x, t); t = fmaf(ch1, v0.y, t);
        t = fmaf(ch2, v0.z, t); t = fmaf(ch3, v0.w, t);
        t = fmaf(ch4, v1.x, t); t = fmaf(ch5, v1.y, t);
        t = fmaf(ch6, v1.z, t); t = fmaf(ch7, v1.w, t);
        a[r] = t;
      }
    }
    const float inv2s = 0.08838834764831845f;  // 1/(2*sqrt(32))
    int cnt[9];
#pragma unroll
    for (int r = 0; r < 9; ++r) cnt[r] = cnt9[ent * 9 + r];
    float m1 = -INFINITY;
#pragma unroll
    for (int r = 0; r < 9; ++r)
      if (cnt[r] > 0) m1 = fmaxf(m1, a[r] * inv2s);
    if (m1 == -INFINITY) {
#pragma unroll
      for (int r = 0; r < 9; ++r) rel2t[ent * 9 + r] = 0.f;
      return;
    }
    float den1 = 1e-16f;
#pragma unroll
    for (int r = 0; r < 9; ++r)
      if (cnt[r] > 0) den1 += (float)cnt[r] * expf(a[r] * inv2s - m1);
#pragma unroll
    for (int r = 0; r < 9; ++r) {
      float rs = expf(a[r] * inv2s - m1) / den1;
      rel2t[ent * 9 + r] = rs * rs * wsql[r];
    }
  }
}

// KG aggregation inner (readlane broadcasts, 4 acc chains) — generic path
__device__ __forceinline__ float kg_agg64(int deg, int lane, int pk, float mk,
                                          const ushort_t* __restrict__ srcbf,
                                          const float* __restrict__ wl) {
  float a0 = 0.f, a1 = 0.f, a2 = 0.f, a3 = 0.f;
  int j = 0;
  for (; j + 4 <= deg; j += 4) {
    int p0 = rl(pk, j), p1 = rl(pk, j + 1), p2 = rl(pk, j + 2), p3 = rl(pk, j + 3);
    float k0 = rlf(mk, j), k1 = rlf(mk, j + 1), k2 = rlf(mk, j + 2), k3 = rlf(mk, j + 3);
    float r0 = bf2f(srcbf[((p0 & 0xFFFFF) << 6) + lane]);
    float r1 = bf2f(srcbf[((p1 & 0xFFFFF) << 6) + lane]);
    float r2 = bf2f(srcbf[((p2 & 0xFFFFF) << 6) + lane]);
    float r3 = bf2f(srcbf[((p3 & 0xFFFFF) << 6) + lane]);
    a0 = fmaf(r0 * wl[(((p0 >> 20) & 15) << 6) + lane], k0, a0);
    a1 = fmaf(r1 * wl[(((p1 >> 20) & 15) << 6) + lane], k1, a1);
    a2 = fmaf(r2 * wl[(((p2 >> 20) & 15) << 6) + lane], k2, a2);
    a3 = fmaf(r3 * wl[(((p3 >> 20) & 15) << 6) + lane], k3, a3);
  }
  for (; j < deg; ++j) {
    int pj = rl(pk, j);
    float kj = rlf(mk, j);
    a0 = fmaf(bf2f(srcbf[((pj & 0xFFFFF) << 6) + lane]) * wl[(((pj >> 20) & 15) << 6) + lane], kj, a0);
  }
  return (a0 + a1) + (a2 + a3);
}

// ---------------- UI aggregation body (readlane broadcasts) ----------------
__device__ __forceinline__ void ui_body(int usr, int lane,
                                        const ushort_t* __restrict__ srcbf,
                                        const float4* __restrict__ sc4,
                                        const float* __restrict__ addb,
                                        float* __restrict__ outp, float* __restrict__ nxt,
                                        const int* __restrict__ uptr,
                                        const int2* __restrict__ cv,
                                        const float* __restrict__ dwl,
                                        const float* __restrict__ latl,
                                        float4* __restrict__ sc4out) {
  float4 s4 = sc4[usr];
  float m = fmaxf(fmaxf(s4.x, s4.y), fmaxf(s4.z, s4.w));
  float e0 = expf(s4.x - m), e1 = expf(s4.y - m), e2 = expf(s4.z - m), e3 = expf(s4.w - m);
  float den = e0 + e1 + e2 + e3;
  float mix = (e0 * dwl[lane] + e1 * dwl[64 + lane] + e2 * dwl[128 + lane] + e3 * dwl[192 + lane]) / den;
  int s = uptr[usr], e = uptr[usr + 1];
  float a0 = 0.f, a1 = 0.f, a2 = 0.f, a3 = 0.f;
  for (int base = s; base < e; base += 64) {
    int c = min(64, e - base);
    int2 cvl = (lane < c) ? cv[base + lane] : make_int2(0, 0);
    int cl = cvl.x;
    float vl = __int_as_float(cvl.y);
    int j = 0;
    for (; j + 8 <= c; j += 8) {
      int c0 = rl(cl, j), c1 = rl(cl, j + 1), c2 = rl(cl, j + 2), c3 = rl(cl, j + 3);
      int c4 = rl(cl, j + 4), c5 = rl(cl, j + 5), c6 = rl(cl, j + 6), c7 = rl(cl, j + 7);
      float v0 = rlf(vl, j), v1 = rlf(vl, j + 1), v2 = rlf(vl, j + 2), v3 = rlf(vl, j + 3);
      float v4 = rlf(vl, j + 4), v5 = rlf(vl, j + 5), v6 = rlf(vl, j + 6), v7 = rlf(vl, j + 7);
      float r0 = bf2f(srcbf[(c0 << 6) + lane]);
      float r1 = bf2f(srcbf[(c1 << 6) + lane]);
      float r2 = bf2f(srcbf[(c2 << 6) + lane]);
      float r3 = bf2f(srcbf[(c3 << 6) + lane]);
      float r4 = bf2f(srcbf[(c4 << 6) + lane]);
      float r5 = bf2f(srcbf[(c5 << 6) + lane]);
      float r6 = bf2f(srcbf[(c6 << 6) + lane]);
      float r7 = bf2f(srcbf[(c7 << 6) + lane]);
      a0 = fmaf(r0, v0, a0); a1 = fmaf(r1, v1, a1);
      a2 = fmaf(r2, v2, a2); a3 = fmaf(r3, v3, a3);
      a0 = fmaf(r4, v4, a0); a1 = fmaf(r5, v5, a1);
      a2 = fmaf(r6, v6, a2); a3 = fmaf(r7, v7, a3);
    }
    for (; j < c; ++j) {
      int cj = rl(cl, j);
      float vj = rlf(vl, j);
      a0 = fmaf(bf2f(srcbf[(cj << 6) + lane]), vj, a0);
    }
  }
  float acc = (a0 + a1) + (a2 + a3);
  float ua = acc * mix + acc;
  float nrm = sqrtf(waveReduceSum(ua * ua));
  float val = ua / fmaxf(nrm, 1e-12f);
  size_t o = (size_t)usr * 64 + lane;
  if (nxt) nxt[o] = val;
  outp[o] = addb[o] + val;
  if (sc4out) {
    // fused hop-2 factor scores: sc4b[usr] = val @ latent^T
    float s0 = waveReduceSum(val * latl[lane]);
    float s1 = waveReduceSum(val * latl[64 + lane]);
    float s2 = waveReduceSum(val * latl[128 + lane]);
    float s3 = waveReduceSum(val * latl[192 + lane]);
    if (lane == 0) sc4out[usr] = make_float4(s0, s1, s2, s3);
  }
}

// ---------------- D1: mask + fused KG hop-1  |  UI hop-1 (+sc4b) ----------------
__global__ void k_mask_kg_ui(const float* __restrict__ ent0,
                             const ushort_t* __restrict__ ent0bf,
                             const int* __restrict__ hptr, const int* __restrict__ packed,
                             const float* __restrict__ rel2t,
                             float* __restrict__ mask_s, const float* __restrict__ weight,
                             float* __restrict__ out_ent, ushort_t* __restrict__ ent1bf,
                             const float4* __restrict__ sc4,
                             float* __restrict__ out_usr,
                             float* __restrict__ usr1, const int* __restrict__ uptr,
                             const int2* __restrict__ cv,
                             const float* __restrict__ user_emb, const float* __restrict__ dw,
                             const float* __restrict__ latent, float4* __restrict__ sc4b) {
  int lane = threadIdx.x & 63, wid = threadIdx.x >> 6;
  if (blockIdx.x < KG_BLOCKS) {
    __shared__ __align__(16) float sh_eh[4][64];
    __shared__ __align__(16) float wl[576];
    for (int i = threadIdx.x; i < 576; i += 256) wl[i] = weight[i];
    int ent = blockIdx.x * 4 + wid;  // always < N_ENT
    int s = hptr[ent], e = hptr[ent + 1];
    float eh = ent0[(size_t)ent * 64 + lane];
    sh_eh[wid][lane] = eh;
    __syncthreads();
    size_t o = (size_t)ent * 64 + lane;
    int deg = e - s;
    if (deg == 0) {
      ent1bf[o] = f2bf(0.f);
      out_ent[o] = eh;
      return;
    }
    if (deg <= 64) {
      // ---- single-pass hot path: group-layout dot + ONLINE-SOFTMAX column
      // accumulation. Rows are loaded exactly ONCE (1 KB/wave-instr); the
      // old second per-row gather pass (kg_agg) is eliminated. ----
      int pk = (lane < deg) ? packed[s + lane] : 0;
      int tb = (pk >> 20) & 15;
      float r2sel = rel2t[ent * 9 + ((lane < deg) ? tb : 0)];
      int g = lane >> 3, part = lane & 7;
      const float4* ehq = (const float4*)(sh_eh[wid] + (part << 3));
      float4 ef0 = ehq[0], ef1 = ehq[1];
      int nch = (deg + 7) >> 3;
      // online-softmax state (all scalars; static indexing only — no scratch)
      float m_run = -INFINITY, den = 0.f;
      float acc0 = 0.f, acc1 = 0.f, acc2 = 0.f, acc3 = 0.f;
      float acc4 = 0.f, acc5 = 0.f, acc6 = 0.f, acc7 = 0.f;
      float trips[8];
#pragma unroll
      for (int cc = 0; cc < 8; ++cc) {
        trips[cc] = -INFINITY;
        if (cc < nch) {
          int j = (cc << 3) + g;  // row handled by this lane's group slot
          int pkj = __shfl(pk, j);  // inactive rows broadcast pk=0 -> row 0 (safe)
          uint4 b = *((const uint4*)(ent0bf + ((size_t)(pkj & 0xFFFFF) << 6)) + part);
          float r0 = bf2f(b.x & 0xFFFFu), r1 = bf2f(b.x >> 16);
          float r2 = bf2f(b.y & 0xFFFFu), r3 = bf2f(b.y >> 16);
          float r4 = bf2f(b.z & 0xFFFFu), r5 = bf2f(b.z >> 16);
          float r6 = bf2f(b.w & 0xFFFFu), r7 = bf2f(b.w >> 16);
          // partial dot over this lane's 8 columns, reduce over part (masks 1,2,4)
          float s0 = r0 * ef0.x, s1 = r2 * ef0.z, s2 = r4 * ef1.x, s3 = r6 * ef1.z;
          s0 = fmaf(r1, ef0.y, s0); s1 = fmaf(r3, ef0.w, s1);
          s2 = fmaf(r5, ef1.y, s2); s3 = fmaf(r7, ef1.w, s3);
          float sv = (s0 + s1) + (s2 + s3);
          sv += __shfl_xor(sv, 1);
          sv += __shfl_xor(sv, 2);
          sv += __shfl_xor(sv, 4);
          float r2j = __shfl(r2sel, j);
          float trip = (j < deg) ? sv + r2j : -INFINITY;
          trips[cc] = trip;
          // chunk max over the 8 rows (reduce over g: masks 8,16,32)
          float mc = trip;
          mc = fmaxf(mc, __shfl_xor(mc, 8));
          mc = fmaxf(mc, __shfl_xor(mc, 16));
          mc = fmaxf(mc, __shfl_xor(mc, 32));
          float m_new = fmaxf(m_run, mc);
          float scale = expf(m_run - m_new);  // first iter: exp(-inf)=0, acc/den are 0
          m_run = m_new;
          float w = (j < deg) ? expf(trip - m_run) : 0.f;
          den = den * scale + w;
          // weighted row accumulate into this lane's 8 columns
          const float4* wp = (const float4*)(wl + (((pkj >> 20) & 15) << 6) + (part << 3));
          float4 w0 = wp[0], w1 = wp[1];
          acc0 = fmaf(w * r0, w0.x, acc0 * scale);
          acc1 = fmaf(w * r1, w0.y, acc1 * scale);
          acc2 = fmaf(w * r2, w0.z, acc2 * scale);
          acc3 = fmaf(w * r3, w0.w, acc3 * scale);
          acc4 = fmaf(w * r4, w1.x, acc4 * scale);
          acc5 = fmaf(w * r5, w1.y, acc5 * scale);
          acc6 = fmaf(w * r6, w1.z, acc6 * scale);
          acc7 = fmaf(w * r7, w1.w, acc7 * scale);
        }
      }
      // full softmax denominator (sum over g)
      float den2 = den;
      den2 += __shfl_xor(den2, 8);
      den2 += __shfl_xor(den2, 16);
      den2 += __shfl_xor(den2, 32);
      den2 += 1e-16f;
      // write mask_s (per-chunk: lanes with part==0 write their group's row)
#pragma unroll
      for (int cc = 0; cc < 8; ++cc) {
        if (cc < nch) {
          int j = (cc << 3) + g;
          if (part == 0 && j < deg) mask_s[s + j] = expf(trips[cc] - m_run) / den2;
        }
      }
      // column sums over g (masks 8,16,32 on each accumulator)
      acc0 += __shfl_xor(acc0, 8); acc0 += __shfl_xor(acc0, 16); acc0 += __shfl_xor(acc0, 32);
      acc1 += __shfl_xor(acc1, 8); acc1 += __shfl_xor(acc1, 16); acc1 += __shfl_xor(acc1, 32);
      acc2 += __shfl_xor(acc2, 8); acc2 += __shfl_xor(acc2, 16); acc2 += __shfl_xor(acc2, 32);
      acc3 += __shfl_xor(acc3, 8); acc3 += __shfl_xor(acc3, 16); acc3 += __shfl_xor(acc3, 32);
      acc4 += __shfl_xor(acc4, 8); acc4 += __shfl_xor(acc4, 16); acc4 += __shfl_xor(acc4, 32);
      acc5 += __shfl_xor(acc5, 8); acc5 += __shfl_xor(acc5, 16); acc5 += __shfl_xor(acc5, 32);
      acc6 += __shfl_xor(acc6, 8); acc6 += __shfl_xor(acc6, 16); acc6 += __shfl_xor(acc6, 32);
      acc7 += __shfl_xor(acc7, 8); acc7 += __shfl_xor(acc7, 16); acc7 += __shfl_xor(acc7, 32);
      // wave transpose: lane l needs colsum[l] = acc[l&7] from lane (l>>3)
      float t0 = __shfl(acc0, g), t1 = __shfl(acc1, g), t2 = __shfl(acc2, g), t3 = __shfl(acc3, g);
      float t4 = __shfl(acc4, g), t5 = __shfl(acc5, g), t6 = __shfl(acc6, g), t7 = __shfl(acc7, g);
      float aggv = t0;
      aggv = (part == 1) ? t1 : aggv;
      aggv = (part == 2) ? t2 : aggv;
      aggv = (part == 3) ? t3 : aggv;
      aggv = (part == 4) ? t4 : aggv;
      aggv = (part == 5) ? t5 : aggv;
      aggv = (part == 6) ? t6 : aggv;
      aggv = (part == 7) ? t7 : aggv;
      float agg = aggv / den2 / (float)deg;
      float nrm = sqrtf(waveReduceSum(agg * agg));
      float val = agg / fmaxf(nrm, 1e-12f);
      ent1bf[o] = f2bf(val);
      out_ent[o] = eh + val;
    } else {
      // ---- generic multi-chunk path ----
      float m2l = -INFINITY;
      for (int base = s; base < e; base += 64) {
        int c = min(64, e - base);
        int pk = (lane < c) ? packed[base + lane] : 0;
        int tb = (pk >> 20) & 15;
        float r2 = rel2t[ent * 9 + ((lane < c) ? tb : 0)];
        int tl = pk & 0xFFFFF;
        const uint4* row = (const uint4*)(ent0bf + (tl << 6));
        const float* ehp = sh_eh[wid];
        float d = 0.f;
#pragma unroll
        for (int q = 0; q < 8; ++q) {
          uint4 a = row[q];
          d += bf2f(a.x & 0xFFFF) * ehp[q * 8 + 0] + bf2f(a.x >> 16) * ehp[q * 8 + 1];
          d += bf2f(a.y & 0xFFFF) * ehp[q * 8 + 2] + bf2f(a.y >> 16) * ehp[q * 8 + 3];
          d += bf2f(a.z & 0xFFFF) * ehp[q * 8 + 4] + bf2f(a.z >> 16) * ehp[q * 8 + 5];
          d += bf2f(a.w & 0xFFFF) * ehp[q * 8 + 6] + bf2f(a.w >> 16) * ehp[q * 8 + 7];
        }
        float trip = d + r2;
        if (lane < c) {
          mask_s[base + lane] = trip;
          m2l = fmaxf(m2l, trip);
        }
      }
      float m2 = waveReduceMax(m2l);
      float denl = 0.f;
      for (int base = s; base < e; base += 64) {
        int c = min(64, e - base);
        denl += (lane < c) ? expf(mask_s[base + lane] - m2) : 0.f;
      }
      float den2 = waveReduceSum(denl) + 1e-16f;
      float acc = 0.f;
      for (int base = s; base < e; base += 64) {
        int c = min(64, e - base);
        int pk = (lane < c) ? packed[base + lane] : 0;
        float mk = 0.f;
        if (lane < c) {
          mk = expf(mask_s[base + lane] - m2) / den2;
          mask_s[base + lane] = mk;
        }
        acc += kg_agg64(c, lane, pk, mk, ent0bf, wl);
      }
      float agg = acc / (float)deg;
      float nrm = sqrtf(waveReduceSum(agg * agg));
      float val = agg / fmaxf(nrm, 1e-12f);
      ent1bf[o] = f2bf(val);
      out_ent[o] = eh + val;
    }
  } else {
    __shared__ float dwl[256];
    __shared__ float latl[256];
    if (threadIdx.x < 256) {
      dwl[threadIdx.x] = dw[threadIdx.x];
      latl[threadIdx.x] = latent[threadIdx.x];
    }
    __syncthreads();
    int usr = (blockIdx.x - KG_BLOCKS) * 4 + wid;  // always < N_USR
    ui_body(usr, lane, ent0bf, sc4, user_emb, out_usr, usr1,
            uptr, cv, dwl, latl, sc4b);
  }
}

// ---------------- D2: KG hop-2 + UI hop-2 ----------------
__global__ void k_hop2(const ushort_t* __restrict__ srcbf,
                       float* __restrict__ out_ent,
                       const int* __restrict__ hptr, const int* __restrict__ packed,
                       const float* __restrict__ mask_s, const float* __restrict__ weight,
                       const float* __restrict__ usr1, float* __restrict__ out_usr,
                       const int* __restrict__ uptr, const int2* __restrict__ cv,
                       const float4* __restrict__ sc4,
                       const float* __restrict__ dw) {
  int lane = threadIdx.x & 63, wid = threadIdx.x >> 6;
  if (blockIdx.x < KG_BLOCKS) {
    __shared__ float wl[576];
    for (int i = threadIdx.x; i < 576; i += 256) wl[i] = weight[i];
    __syncthreads();
    int ent = blockIdx.x * 4 + wid;
    int s = hptr[ent], e = hptr[ent + 1];
    float acc = 0.f;
    for (int base = s; base < e; base += 64) {
      int c = min(64, e - base);
      int pk = (lane < c) ? packed[base + lane] : 0;
      float mk = (lane < c) ? mask_s[base + lane] : 0.f;
      acc += kg_agg64(c, lane, pk, mk, srcbf, wl);
    }
    float n = (float)(e - s);
    float agg = acc / fmaxf(n, 1.0f);
    float nrm = sqrtf(waveReduceSum(agg * agg));
    float val = agg / fmaxf(nrm, 1e-12f);
    size_t o = (size_t)ent * 64 + lane;
    out_ent[o] = out_ent[o] + val;
  } else {
    __shared__ float dwl[256];
    if (threadIdx.x < 256) dwl[threadIdx.x] = dw[threadIdx.x];
    __syncthreads();
    int usr = (blockIdx.x - KG_BLOCKS) * 4 + wid;
    ui_body(usr, lane, srcbf, sc4, out_usr, out_usr, nullptr,
            uptr, cv, dwl, nullptr, nullptr);
  }
}

extern "C" void kernel_launch(void* const* d_in, const int* in_sizes, int n_in,
                              void* d_out, int out_size, void* d_ws, size_t ws_size,
                              hipStream_t stream) {
  const float* user_emb = (const float*)d_in[0];
  const float* entity_emb = (const float*)d_in[1];
  const float* latent = (const float*)d_in[2];
  const float* weight = (const float*)d_in[3];
  const float* disen = (const float*)d_in[4];
  const float* kgW = (const float*)d_in[5];
  const float* ui_vals = (const float*)d_in[6];
  const int* edge_index = (const int*)d_in[7];
  const int* edge_type = (const int*)d_in[8];
  const int* ui_rows = (const int*)d_in[9];
  const int* ui_cols = (const int*)d_in[10];
  const int* head = edge_index;
  const int* tail = edge_index + N_EDGE;

  char* ws = (char*)d_ws;
  size_t o = 0;
  auto alloc = [&](size_t bytes) -> char* {
    char* p = ws + o;
    o += (bytes + 255) & ~(size_t)255;
    return p;
  };
  int* head_ptr = (int*)alloc((N_ENT + 1) * 4);
  int* head_cur = (int*)alloc((size_t)N_ENT * 4);
  int* ui_ptr = (int*)alloc((N_USR + 1) * 4);
  int* ui_cur = (int*)alloc((size_t)N_USR * 4);
  int* bsum_h = (int*)alloc(256 * 4);
  int* bsum_u = (int*)alloc(256 * 4);
  int* packed = (int*)alloc((size_t)N_EDGE * 4);
  int2* cv = (int2*)alloc((size_t)N_EDGE * 8);
  float* mask_s = (float*)alloc((size_t)N_EDGE * 4);
  ushort_t* ent0bf = (ushort_t*)alloc((size_t)N_ENT * 64 * 2);
  ushort_t* ent1bf = (ushort_t*)alloc((size_t)N_ENT * 64 * 2);
  float* usr1 = (float*)alloc((size_t)N_USR * 64 * 4);
  int* cnt9 = (int*)alloc((size_t)N_ENT * 9 * 4);
  float* rel2t = (float*)alloc((size_t)N_ENT * 9 * 4);
  float4* sc4a = (float4*)alloc((size_t)N_USR * 16);
  float4* sc4b = (float4*)alloc((size_t)N_USR * 16);
  float* V = (float*)alloc(9 * 64 * 4);
  float* wsq = (float*)alloc(16 * 4);
  float* dw = (float*)alloc(4 * 64 * 4);
  if (o > ws_size) return;

  float* out_ent = (float*)d_out;
  float* out_usr = out_ent + (size_t)N_ENT * 64;
  float* out_cor = out_ent + (size_t)N_ENT * 64 + (size_t)N_USR * 64;

  hipMemsetAsync(ui_cur, 0, (size_t)N_USR * 4, stream);
  hipMemsetAsync(cnt9, 0, (size_t)N_ENT * 9 * 4, stream);

  // K1: bf16 convert + count + prep + sc(user)
  k_pre<<<TB_BLOCKS + CNT_BLOCKS + 1 + SC_BLOCKS, 256, 0, stream>>>(
      entity_emb, ent0bf, head, ui_rows, edge_type, ui_cur, cnt9,
      weight, kgW, disen, V, wsq, dw, out_cor, user_emb, latent, sc4a);

  int nbh = (N_ENT + 1023) / 1024, nbu = (N_USR + 1023) / 1024;
  // K2: fused scan-reduce
  k_scanred<<<nbh + nbu, 256, 0, stream>>>(cnt9, ui_cur, bsum_h, bsum_u, nbh);
  // K3: block-sum exclusive scans
  k_scan_tops<<<1, 64, 0, stream>>>(bsum_h, nbh, bsum_u, nbu, head_ptr, N_ENT, ui_ptr, N_USR, N_EDGE);
  // K4: fused scan-final
  k_scanfin<<<nbh + nbu, 256, 0, stream>>>(cnt9, bsum_h, bsum_u,
                                           head_ptr, head_cur, ui_ptr, ui_cur, nbh);
  // K5: build + rel2
  k_build_rel2<<<BUILD_BLOCKS + REL2_BLOCKS, 256, 0, stream>>>(
      head, tail, edge_type, ui_rows, ui_cols, ui_vals,
      head_cur, ui_cur, packed, cv, ent0bf, V, wsq, cnt9, rel2t);

  // D1: mask + fused KG hop-1 + UI hop-1 (+ sc4b epilogue)
  k_mask_kg_ui<<<KG_BLOCKS + UI_BLOCKS, 256, 0, stream>>>(
      entity_emb, ent0bf, head_ptr, packed, rel2t, mask_s, weight,
      out_ent, ent1bf, sc4a, out_usr, usr1, ui_ptr, cv, user_emb, dw, latent, sc4b);

  // D2: KG hop-2 + UI hop-2
  k_hop2<<<KG_BLOCKS + UI_BLOCKS, 256, 0, stream>>>(
      ent1bf, out_ent, head_ptr, packed, mask_s, weight,
      usr1, out_usr, ui_ptr, cv, sc4b, dw);
}

// Round 3
// 573.036 us; speedup vs baseline: 1.2765x; 1.0390x over previous
//
#include <hip/hip_runtime.h>
#include <math.h>

#define N_ENT 100000
#define N_USR 50000
#define N_EDGE 1000000
#define TEMPC 0.2f
#define KG_BLOCKS (N_ENT / 4)   // 25000, exact
#define UI_BLOCKS (N_USR / 4)   // 12500, exact

// fused-kernel block ranges
#define TB_BLOCKS 6250   // ceil(N_ENT*64/4 / 256) : bf16 convert (float4 granules)
#define CNT_BLOCKS 489   // ceil(N_EDGE/8 / 256) : count, 8 edges/thread
#define SC_BLOCKS 196    // ceil(N_USR / 256)
#define BUILD_BLOCKS 489 // ceil(N_EDGE/8 / 256)
#define REL2_BLOCKS 391  // ceil(N_ENT / 256)

#define WLS 68   // padded stride for weight rows in LDS (bank-rotates relations)

typedef unsigned short ushort_t;

__device__ __forceinline__ float waveReduceSum(float x) {
#pragma unroll
  for (int d = 32; d > 0; d >>= 1) x += __shfl_xor(x, d);
  return x;
}
__device__ __forceinline__ float waveReduceMax(float x) {
#pragma unroll
  for (int d = 32; d > 0; d >>= 1) x = fmaxf(x, __shfl_xor(x, d));
  return x;
}
__device__ __forceinline__ int waveReduceSumI(int x) {
#pragma unroll
  for (int d = 32; d > 0; d >>= 1) x += __shfl_xor(x, d);
  return x;
}
__device__ __forceinline__ float bf2f(unsigned int u16) {
  union { unsigned int i; float f; } v;
  v.i = u16 << 16;
  return v.f;
}
__device__ __forceinline__ ushort_t f2bf(float f) {
  union { unsigned int i; float f; } v;
  v.f = f;
  unsigned int u = v.i;
  u = (u + 0x7FFFu + ((u >> 16) & 1u)) >> 16;
  return (ushort_t)u;
}
// wave-uniform broadcast via v_readlane -> SGPR (cheap scalar addressing downstream)
__device__ __forceinline__ int rl(int v, int l) { return __builtin_amdgcn_readlane(v, l); }
__device__ __forceinline__ float rlf(float v, int l) {
  return __int_as_float(__builtin_amdgcn_readlane(__float_as_int(v), l));
}

// column-partial reduce over g (masks 8/16/32) + 8x8 wave transpose:
// on entry lane holds partials for columns part*8+k; on exit lane l holds colsum[l].
__device__ __forceinline__ float colRT(float a0, float a1, float a2, float a3,
                                       float a4, float a5, float a6, float a7,
                                       int g, int part) {
#define RED3(x) x += __shfl_xor(x, 8); x += __shfl_xor(x, 16); x += __shfl_xor(x, 32);
  RED3(a0) RED3(a1) RED3(a2) RED3(a3) RED3(a4) RED3(a5) RED3(a6) RED3(a7)
#undef RED3
  float t0 = __shfl(a0, g), t1 = __shfl(a1, g), t2 = __shfl(a2, g), t3 = __shfl(a3, g);
  float t4 = __shfl(a4, g), t5 = __shfl(a5, g), t6 = __shfl(a6, g), t7 = __shfl(a7, g);
  float r = t0;
  r = (part == 1) ? t1 : r;
  r = (part == 2) ? t2 : r;
  r = (part == 3) ? t3 : r;
  r = (part == 4) ? t4 : r;
  r = (part == 5) ? t5 : r;
  r = (part == 6) ? t6 : r;
  r = (part == 7) ? t7 : r;
  return r;
}

// ============ K1: bf16 convert | edge count (8/thr) | prep | sc(user) ============
__global__ void k_pre(const float* __restrict__ ent0, ushort_t* __restrict__ ent0bf,
                      const int* __restrict__ head, const int* __restrict__ uir,
                      const int* __restrict__ etype,
                      int* __restrict__ cnt_u, int* __restrict__ cnt9,
                      const float* __restrict__ weight, const float* __restrict__ kgW,
                      const float* __restrict__ disen,
                      float* __restrict__ V, float* __restrict__ wsq,
                      float* __restrict__ dw, float* __restrict__ cor_out,
                      const float* __restrict__ user_emb, const float* __restrict__ latent,
                      float4* __restrict__ sc4a) {
  int bid = blockIdx.x;
  if (bid < TB_BLOCKS) {
    int i = bid * 256 + threadIdx.x;
    if (i < N_ENT * 16) {
      float4 v = ((const float4*)ent0)[i];
      ushort4 o;
      o.x = f2bf(v.x); o.y = f2bf(v.y); o.z = f2bf(v.z); o.w = f2bf(v.w);
      ((ushort4*)ent0bf)[i] = o;
    }
  } else if (bid < TB_BLOCKS + CNT_BLOCKS) {
    int i0 = ((bid - TB_BLOCKS) * 256 + threadIdx.x) * 8;
    if (i0 < N_EDGE) {
      int4 ha = *(const int4*)(head + i0), hb = *(const int4*)(head + i0 + 4);
      int4 ea = *(const int4*)(etype + i0), eb = *(const int4*)(etype + i0 + 4);
      int4 ua = *(const int4*)(uir + i0), ub = *(const int4*)(uir + i0 + 4);
      atomicAdd(&cnt9[ha.x * 9 + (ea.x - 1)], 1);
      atomicAdd(&cnt9[ha.y * 9 + (ea.y - 1)], 1);
      atomicAdd(&cnt9[ha.z * 9 + (ea.z - 1)], 1);
      atomicAdd(&cnt9[ha.w * 9 + (ea.w - 1)], 1);
      atomicAdd(&cnt9[hb.x * 9 + (eb.x - 1)], 1);
      atomicAdd(&cnt9[hb.y * 9 + (eb.y - 1)], 1);
      atomicAdd(&cnt9[hb.z * 9 + (eb.z - 1)], 1);
      atomicAdd(&cnt9[hb.w * 9 + (eb.w - 1)], 1);
      atomicAdd(&cnt_u[ua.x], 1);
      atomicAdd(&cnt_u[ua.y], 1);
      atomicAdd(&cnt_u[ua.z], 1);
      atomicAdd(&cnt_u[ua.w], 1);
      atomicAdd(&cnt_u[ub.x], 1);
      atomicAdd(&cnt_u[ub.y], 1);
      atomicAdd(&cnt_u[ub.z], 1);
      atomicAdd(&cnt_u[ub.w], 1);
    }
  } else if (bid == TB_BLOCKS + CNT_BLOCKS) {
    // ---- prep: V=(W W^T)w_r via T-factorization, wsq, dw, cor ----
    __shared__ float T[9 * 64];
    __shared__ float sm[4 * 9];
    int tid = threadIdx.x;
    for (int e = tid; e < 9 * 64; e += 256) {
      int r = e >> 6, d = e & 63;
      float s = 0.f;
      for (int k = 0; k < 64; ++k) s += kgW[k * 64 + d] * weight[r * 64 + k];
      T[e] = s;
    }
    if (tid < 4) {
      float m = -INFINITY;
      for (int r = 0; r < 9; ++r) m = fmaxf(m, disen[tid * 9 + r]);
      float den = 0.f;
      float ex[9];
      for (int r = 0; r < 9; ++r) { ex[r] = expf(disen[tid * 9 + r] - m); den += ex[r]; }
      for (int r = 0; r < 9; ++r) sm[tid * 9 + r] = ex[r] / den;
    }
    __syncthreads();
    for (int e = tid; e < 9 * 64; e += 256) {
      int r = e >> 6, i = e & 63;
      float s = 0.f;
      for (int d = 0; d < 64; ++d) s += kgW[i * 64 + d] * T[r * 64 + d];
      V[e] = s;
    }
    if (tid < 9) {
      float s = 0.f;
      for (int c = 0; c < 64; ++c) { float w = weight[tid * 64 + c]; s += w * w; }
      wsq[tid] = s;
    }
    for (int e = tid; e < 4 * 64; e += 256) {
      int f = e >> 6, c = e & 63;
      float s = 0.f;
      for (int r = 0; r < 9; ++r) s += sm[f * 9 + r] * weight[r * 64 + c];
      dw[e] = s;
    }
    if (tid == 0) {
      float rowsum[4];
      for (int f = 0; f < 4; ++f) {
        float s = 0.f;
        for (int j = 0; j < 9; ++j) s += disen[f * 9 + j];
        rowsum[f] = s;
      }
      float cor = 0.f;
      for (int i = 0; i < 9; ++i) {
        float n2 = 0.f, ttl = 0.f;
        for (int f = 0; f < 4; ++f) {
          float v = disen[f * 9 + i];
          n2 += v * v;
          ttl += v * rowsum[f];
        }
        float nrm = sqrtf(n2);
        float pos = 0.f;
        for (int f = 0; f < 4; ++f) {
          float v = disen[f * 9 + i] / nrm;
          pos += v * v;
        }
        cor += (ttl - pos) / TEMPC;
      }
      *cor_out = cor;
    }
  } else {
    // ---- sc on user_emb -> sc4a ----
    __shared__ __align__(16) float lat[256];
    if (threadIdx.x < 256) lat[threadIdx.x] = latent[threadIdx.x];
    __syncthreads();
    int u = (bid - TB_BLOCKS - CNT_BLOCKS - 1) * 256 + threadIdx.x;
    if (u >= N_USR) return;
    float a0 = 0.f, a1 = 0.f, a2 = 0.f, a3 = 0.f;
    const float4* row = (const float4*)(user_emb + (size_t)u * 64);
#pragma unroll
    for (int q = 0; q < 16; ++q) {
      float4 v = row[q];
      float4 l0 = *(const float4*)(lat + 0 * 64 + q * 4);
      float4 l1 = *(const float4*)(lat + 1 * 64 + q * 4);
      float4 l2 = *(const float4*)(lat + 2 * 64 + q * 4);
      float4 l3 = *(const float4*)(lat + 3 * 64 + q * 4);
      a0 = fmaf(v.x, l0.x, a0); a0 = fmaf(v.y, l0.y, a0); a0 = fmaf(v.z, l0.z, a0); a0 = fmaf(v.w, l0.w, a0);
      a1 = fmaf(v.x, l1.x, a1); a1 = fmaf(v.y, l1.y, a1); a1 = fmaf(v.z, l1.z, a1); a1 = fmaf(v.w, l1.w, a1);
      a2 = fmaf(v.x, l2.x, a2); a2 = fmaf(v.y, l2.y, a2); a2 = fmaf(v.z, l2.z, a2); a2 = fmaf(v.w, l2.w, a2);
      a3 = fmaf(v.x, l3.x, a3); a3 = fmaf(v.y, l3.y, a3); a3 = fmaf(v.z, l3.z, a3); a3 = fmaf(v.w, l3.w, a3);
    }
    sc4a[u] = make_float4(a0, a1, a2, a3);
  }
}

// ============ K2: fused scan-reduce (head from cnt9 rowsums | ui) ============
__global__ void k_scanred(const int* __restrict__ cnt9, const int* __restrict__ cnt_u,
                          int* __restrict__ bsum_h, int* __restrict__ bsum_u, int nbh) {
  int b = blockIdx.x, tid = threadIdx.x;
  int s = 0;
  if (b < nbh) {
    int i0 = b * 1024 + tid * 4;
#pragma unroll
    for (int k = 0; k < 4; ++k)
      if (i0 + k < N_ENT) {
        int base = (i0 + k) * 9;
#pragma unroll
        for (int r = 0; r < 9; ++r) s += cnt9[base + r];
      }
  } else {
    int i0 = (b - nbh) * 1024 + tid * 4;
#pragma unroll
    for (int k = 0; k < 4; ++k)
      if (i0 + k < N_USR) s += cnt_u[i0 + k];
  }
  s = waveReduceSumI(s);
  __shared__ int l[4];
  int lane = tid & 63, wid = tid >> 6;
  if (lane == 0) l[wid] = s;
  __syncthreads();
  if (tid == 0) {
    int v = l[0] + l[1] + l[2] + l[3];
    if (b < nbh) bsum_h[b] = v; else bsum_u[b - nbh] = v;
  }
}

__global__ void k_scan_tops(int* bsA, int nA, int* bsB, int nB,
                            int* ptrA, int NA, int* ptrB, int NB, int total) {
  if (threadIdx.x == 0) {
    int a = 0;
    for (int i = 0; i < nA; ++i) { int t = bsA[i]; bsA[i] = a; a += t; }
    ptrA[NA] = total;
  }
  if (threadIdx.x == 1) {
    int a = 0;
    for (int i = 0; i < nB; ++i) { int t = bsB[i]; bsB[i] = a; a += t; }
    ptrB[NB] = total;
  }
}

// ============ K4: fused scan-final (head from cnt9 | ui) ============
__global__ void k_scanfin(const int* __restrict__ cnt9, const int* __restrict__ bsum_h,
                          const int* __restrict__ bsum_u,
                          int* __restrict__ head_ptr, int* __restrict__ head_cur,
                          int* __restrict__ ui_ptr, int* __restrict__ ui_cur, int nbh) {
  int b = blockIdx.x, tid = threadIdx.x;
  bool isH = (b < nbh);
  int bl = isH ? b : b - nbh;
  int n = isH ? N_ENT : N_USR;
  int i0 = bl * 1024 + tid * 4;
  int c[4];
  int s = 0;
  int loc[4];
#pragma unroll
  for (int k = 0; k < 4; ++k) {
    int v = 0;
    if (i0 + k < n) {
      if (isH) {
        int base = (i0 + k) * 9;
#pragma unroll
        for (int r = 0; r < 9; ++r) v += cnt9[base + r];
      } else {
        v = ui_cur[i0 + k];
      }
    }
    c[k] = v;
    loc[k] = s;
    s += v;
  }
  int lane = tid & 63, wid = tid >> 6;
  int x = s;
#pragma unroll
  for (int d = 1; d < 64; d <<= 1) {
    int y = __shfl_up(x, d);
    if (lane >= d) x += y;
  }
  __shared__ int l[4];
  if (lane == 63) l[wid] = x;
  __syncthreads();
  if (tid == 0) {
    int a = 0;
    for (int w = 0; w < 4; ++w) { int t = l[w]; l[w] = a; a += t; }
  }
  __syncthreads();
  int excl = x - s + l[wid] + (isH ? bsum_h[bl] : bsum_u[bl]);
#pragma unroll
  for (int k = 0; k < 4; ++k) {
    if (i0 + k < n) {
      int v = excl + loc[k];
      if (isH) {
        head_ptr[i0 + k] = v;
        head_cur[i0 + k] = v;
      } else {
        ui_ptr[i0 + k] = v;
        ui_cur[i0 + k] = v;
      }
    }
  }
}

// ============ K5: build (8/thr) | rel2 ============
__global__ void k_build_rel2(const int* __restrict__ head, const int* __restrict__ tail,
                             const int* __restrict__ etype,
                             const int* __restrict__ uir, const int* __restrict__ uic,
                             const float* __restrict__ uival,
                             int* __restrict__ cur_h, int* __restrict__ cur_u,
                             int* __restrict__ packed, int2* __restrict__ cv,
                             const ushort_t* __restrict__ ent0bf, const float* __restrict__ V,
                             const float* __restrict__ wsq, const int* __restrict__ cnt9,
                             float* __restrict__ rel2t) {
  if (blockIdx.x < BUILD_BLOCKS) {
    int i0 = (blockIdx.x * 256 + threadIdx.x) * 8;
    if (i0 >= N_EDGE) return;
    int4 ha = *(const int4*)(head + i0), hb = *(const int4*)(head + i0 + 4);
    int4 ta = *(const int4*)(tail + i0), tb4 = *(const int4*)(tail + i0 + 4);
    int4 ea = *(const int4*)(etype + i0), eb = *(const int4*)(etype + i0 + 4);
    int4 ua = *(const int4*)(uir + i0), ub = *(const int4*)(uir + i0 + 4);
    int4 ca = *(const int4*)(uic + i0), cb = *(const int4*)(uic + i0 + 4);
    float4 va = *(const float4*)(uival + i0), vb = *(const float4*)(uival + i0 + 4);
    int p0 = atomicAdd(&cur_h[ha.x], 1);
    int p1 = atomicAdd(&cur_h[ha.y], 1);
    int p2 = atomicAdd(&cur_h[ha.z], 1);
    int p3 = atomicAdd(&cur_h[ha.w], 1);
    int p4 = atomicAdd(&cur_h[hb.x], 1);
    int p5 = atomicAdd(&cur_h[hb.y], 1);
    int p6 = atomicAdd(&cur_h[hb.z], 1);
    int p7 = atomicAdd(&cur_h[hb.w], 1);
    int q0 = atomicAdd(&cur_u[ua.x], 1);
    int q1 = atomicAdd(&cur_u[ua.y], 1);
    int q2 = atomicAdd(&cur_u[ua.z], 1);
    int q3 = atomicAdd(&cur_u[ua.w], 1);
    int q4 = atomicAdd(&cur_u[ub.x], 1);
    int q5 = atomicAdd(&cur_u[ub.y], 1);
    int q6 = atomicAdd(&cur_u[ub.z], 1);
    int q7 = atomicAdd(&cur_u[ub.w], 1);
    packed[p0] = (ta.x & 0xFFFFF) | ((ea.x - 1) << 20);
    packed[p1] = (ta.y & 0xFFFFF) | ((ea.y - 1) << 20);
    packed[p2] = (ta.z & 0xFFFFF) | ((ea.z - 1) << 20);
    packed[p3] = (ta.w & 0xFFFFF) | ((ea.w - 1) << 20);
    packed[p4] = (tb4.x & 0xFFFFF) | ((eb.x - 1) << 20);
    packed[p5] = (tb4.y & 0xFFFFF) | ((eb.y - 1) << 20);
    packed[p6] = (tb4.z & 0xFFFFF) | ((eb.z - 1) << 20);
    packed[p7] = (tb4.w & 0xFFFFF) | ((eb.w - 1) << 20);
    cv[q0] = make_int2(ca.x, __float_as_int(va.x));
    cv[q1] = make_int2(ca.y, __float_as_int(va.y));
    cv[q2] = make_int2(ca.z, __float_as_int(va.z));
    cv[q3] = make_int2(ca.w, __float_as_int(va.w));
    cv[q4] = make_int2(cb.x, __float_as_int(vb.x));
    cv[q5] = make_int2(cb.y, __float_as_int(vb.y));
    cv[q6] = make_int2(cb.z, __float_as_int(vb.z));
    cv[q7] = make_int2(cb.w, __float_as_int(vb.w));
  } else {
    // ---- rel2: dense per-entity relation softmax table ----
    __shared__ __align__(16) float Vl[576];
    __shared__ float wsql[9];
    for (int i = threadIdx.x; i < 576; i += 256) Vl[i] = V[i];
    if (threadIdx.x < 9) wsql[threadIdx.x] = wsq[threadIdx.x];
    __syncthreads();
    int ent = (blockIdx.x - BUILD_BLOCKS) * 256 + threadIdx.x;
    if (ent >= N_ENT) return;
    float a[9] = {0, 0, 0, 0, 0, 0, 0, 0, 0};
    const uint4* row = (const uint4*)(ent0bf + (ent << 6));
#pragma unroll
    for (int q = 0; q < 8; ++q) {
      uint4 b = row[q];
      float ch0 = bf2f(b.x & 0xFFFFu), ch1 = bf2f(b.x >> 16);
      float ch2 = bf2f(b.y & 0xFFFFu), ch3 = bf2f(b.y >> 16);
      float ch4 = bf2f(b.z & 0xFFFFu), ch5 = bf2f(b.z >> 16);
      float ch6 = bf2f(b.w & 0xFFFFu), ch7 = bf2f(b.w >> 16);
#pragma unroll
      for (int r = 0; r < 9; ++r) {
        const float4* vp = (const float4*)(Vl + r * 64 + q * 8);
        float4 v0 = vp[0], v1 = vp[1];
        float t = a[r];
        t = fmaf(ch0, v0.x, t); t = fmaf(ch1, v0.y, t);
        t = fmaf(ch2, v0.z, t); t = fmaf(ch3, v0.w, t);
        t = fmaf(ch4, v1.x, t); t = fmaf(ch5, v1.y, t);
        t = fmaf(ch6, v1.z, t); t = fmaf(ch7, v1.w, t);
        a[r] = t;
      }
    }
    const float inv2s = 0.08838834764831845f;  // 1/(2*sqrt(32))
    int cnt[9];
#pragma unroll
    for (int r = 0; r < 9; ++r) cnt[r] = cnt9[ent * 9 + r];
    float m1 = -INFINITY;
#pragma unroll
    for (int r = 0; r < 9; ++r)
      if (cnt[r] > 0) m1 = fmaxf(m1, a[r] * inv2s);
    if (m1 == -INFINITY) {
#pragma unroll
      for (int r = 0; r < 9; ++r) rel2t[ent * 9 + r] = 0.f;
      return;
    }
    float den1 = 1e-16f;
#pragma unroll
    for (int r = 0; r < 9; ++r)
      if (cnt[r] > 0) den1 += (float)cnt[r] * expf(a[r] * inv2s - m1);
#pragma unroll
    for (int r = 0; r < 9; ++r) {
      float rs = expf(a[r] * inv2s - m1) / den1;
      rel2t[ent * 9 + r] = rs * rs * wsql[r];
    }
  }
}

// KG aggregation inner (readlane broadcasts, 4 acc chains) — generic fallback
__device__ __forceinline__ float kg_agg64(int deg, int lane, int pk, float mk,
                                          const ushort_t* __restrict__ srcbf,
                                          const float* __restrict__ wl) {
  float a0 = 0.f, a1 = 0.f, a2 = 0.f, a3 = 0.f;
  int j = 0;
  for (; j + 4 <= deg; j += 4) {
    int p0 = rl(pk, j), p1 = rl(pk, j + 1), p2 = rl(pk, j + 2), p3 = rl(pk, j + 3);
    float k0 = rlf(mk, j), k1 = rlf(mk, j + 1), k2 = rlf(mk, j + 2), k3 = rlf(mk, j + 3);
    float r0 = bf2f(srcbf[((p0 & 0xFFFFF) << 6) + lane]);
    float r1 = bf2f(srcbf[((p1 & 0xFFFFF) << 6) + lane]);
    float r2 = bf2f(srcbf[((p2 & 0xFFFFF) << 6) + lane]);
    float r3 = bf2f(srcbf[((p3 & 0xFFFFF) << 6) + lane]);
    a0 = fmaf(r0 * wl[((p0 >> 20) & 15) * WLS + lane], k0, a0);
    a1 = fmaf(r1 * wl[((p1 >> 20) & 15) * WLS + lane], k1, a1);
    a2 = fmaf(r2 * wl[((p2 >> 20) & 15) * WLS + lane], k2, a2);
    a3 = fmaf(r3 * wl[((p3 >> 20) & 15) * WLS + lane], k3, a3);
  }
  for (; j < deg; ++j) {
    int pj = rl(pk, j);
    float kj = rlf(mk, j);
    a0 = fmaf(bf2f(srcbf[((pj & 0xFFFFF) << 6) + lane]) * wl[((pj >> 20) & 15) * WLS + lane], kj, a0);
  }
  return (a0 + a1) + (a2 + a3);
}

// ---------------- UI aggregation body (group-layout single-pass) ----------------
__device__ __forceinline__ void ui_body(int usr, int lane,
                                        const ushort_t* __restrict__ srcbf,
                                        const float4* __restrict__ sc4,
                                        const float* __restrict__ addb,
                                        float* __restrict__ outp, float* __restrict__ nxt,
                                        const int* __restrict__ uptr,
                                        const int2* __restrict__ cv,
                                        const float* __restrict__ dwl,
                                        const float* __restrict__ latl,
                                        float4* __restrict__ sc4out) {
  float4 s4 = sc4[usr];
  float m = fmaxf(fmaxf(s4.x, s4.y), fmaxf(s4.z, s4.w));
  float e0 = expf(s4.x - m), e1 = expf(s4.y - m), e2 = expf(s4.z - m), e3 = expf(s4.w - m);
  float den = e0 + e1 + e2 + e3;
  float mix = (e0 * dwl[lane] + e1 * dwl[64 + lane] + e2 * dwl[128 + lane] + e3 * dwl[192 + lane]) / den;
  int s = uptr[usr], e = uptr[usr + 1];
  int g = lane >> 3, part = lane & 7;
  float a0 = 0.f, a1 = 0.f, a2 = 0.f, a3 = 0.f;
  float a4 = 0.f, a5 = 0.f, a6 = 0.f, a7 = 0.f;
  for (int base = s; base < e; base += 64) {
    int c = min(64, e - base);
    int2 cvl = (lane < c) ? cv[base + lane] : make_int2(0, 0);
    int cl = cvl.x;
    float vl = __int_as_float(cvl.y);
    int nch = (c + 7) >> 3;
#pragma unroll
    for (int cc = 0; cc < 8; ++cc) {
      if (cc < nch) {
        int j = (cc << 3) + g;
        int cj = __shfl(cl, j);       // inactive rows broadcast 0 -> row 0, vj=0
        float vj = __shfl(vl, j);
        uint4 b = *((const uint4*)(srcbf + ((size_t)cj << 6)) + part);
        a0 = fmaf(bf2f(b.x & 0xFFFFu), vj, a0);
        a1 = fmaf(bf2f(b.x >> 16), vj, a1);
        a2 = fmaf(bf2f(b.y & 0xFFFFu), vj, a2);
        a3 = fmaf(bf2f(b.y >> 16), vj, a3);
        a4 = fmaf(bf2f(b.z & 0xFFFFu), vj, a4);
        a5 = fmaf(bf2f(b.z >> 16), vj, a5);
        a6 = fmaf(bf2f(b.w & 0xFFFFu), vj, a6);
        a7 = fmaf(bf2f(b.w >> 16), vj, a7);
      }
    }
  }
  float acc = colRT(a0, a1, a2, a3, a4, a5, a6, a7, g, part);
  float ua = acc * mix + acc;
  float nrm = sqrtf(waveReduceSum(ua * ua));
  float val = ua / fmaxf(nrm, 1e-12f);
  size_t o = (size_t)usr * 64 + lane;
  if (nxt) nxt[o] = val;
  outp[o] = addb[o] + val;
  if (sc4out) {
    // fused hop-2 factor scores: sc4b[usr] = val @ latent^T
    float s0 = waveReduceSum(val * latl[lane]);
    float s1 = waveReduceSum(val * latl[64 + lane]);
    float s2 = waveReduceSum(val * latl[128 + lane]);
    float s3 = waveReduceSum(val * latl[192 + lane]);
    if (lane == 0) sc4out[usr] = make_float4(s0, s1, s2, s3);
  }
}

// ---------------- D1: mask + fused KG hop-1  |  UI hop-1 (+sc4b) ----------------
__global__ void k_mask_kg_ui(const float* __restrict__ ent0,
                             const ushort_t* __restrict__ ent0bf,
                             const int* __restrict__ hptr, const int* __restrict__ packed,
                             const float* __restrict__ rel2t,
                             float* __restrict__ mask_s, const float* __restrict__ weight,
                             float* __restrict__ out_ent, ushort_t* __restrict__ ent1bf,
                             const float4* __restrict__ sc4,
                             float* __restrict__ out_usr,
                             float* __restrict__ usr1, const int* __restrict__ uptr,
                             const int2* __restrict__ cv,
                             const float* __restrict__ user_emb, const float* __restrict__ dw,
                             const float* __restrict__ latent, float4* __restrict__ sc4b) {
  int lane = threadIdx.x & 63, wid = threadIdx.x >> 6;
  if (blockIdx.x < KG_BLOCKS) {
    __shared__ __align__(16) float sh_eh[4][64];
    __shared__ __align__(16) float wl[9 * WLS];
    for (int i = threadIdx.x; i < 576; i += 256) wl[(i >> 6) * WLS + (i & 63)] = weight[i];
    int ent = blockIdx.x * 4 + wid;  // always < N_ENT
    int s = hptr[ent], e = hptr[ent + 1];
    float eh = ent0[(size_t)ent * 64 + lane];
    sh_eh[wid][lane] = eh;
    __syncthreads();
    size_t o = (size_t)ent * 64 + lane;
    int deg = e - s;
    if (deg == 0) {
      ent1bf[o] = f2bf(0.f);
      out_ent[o] = eh;
      return;
    }
    if (deg <= 64) {
      // ---- single-pass hot path: group-layout dot + DIRECT-EXP softmax.
      // Scores are bounded (|dot| ~ 0.1, rel2 < 1) so exp needs no max-shift;
      // this removes the per-chunk max butterflies and rescale chains. ----
      int pk = (lane < deg) ? packed[s + lane] : 0;
      int tb = (pk >> 20) & 15;
      float r2sel = rel2t[ent * 9 + ((lane < deg) ? tb : 0)];
      int g = lane >> 3, part = lane & 7;
      const float4* ehq = (const float4*)(sh_eh[wid] + (part << 3));
      float4 ef0 = ehq[0], ef1 = ehq[1];
      int nch = (deg + 7) >> 3;
      float den = 0.f;
      float acc0 = 0.f, acc1 = 0.f, acc2 = 0.f, acc3 = 0.f;
      float acc4 = 0.f, acc5 = 0.f, acc6 = 0.f, acc7 = 0.f;
      float ws8[8];
#pragma unroll
      for (int cc = 0; cc < 8; ++cc) {
        ws8[cc] = 0.f;
        if (cc < nch) {
          int j = (cc << 3) + g;  // row handled by this lane's group slot
          int pkj = __shfl(pk, j);  // inactive rows broadcast pk=0 -> row 0 (safe)
          uint4 b = *((const uint4*)(ent0bf + ((size_t)(pkj & 0xFFFFF) << 6)) + part);
          float r0 = bf2f(b.x & 0xFFFFu), r1 = bf2f(b.x >> 16);
          float r2 = bf2f(b.y & 0xFFFFu), r3 = bf2f(b.y >> 16);
          float r4 = bf2f(b.z & 0xFFFFu), r5 = bf2f(b.z >> 16);
          float r6 = bf2f(b.w & 0xFFFFu), r7 = bf2f(b.w >> 16);
          // partial dot over this lane's 8 columns, reduce over part (masks 1,2,4)
          float s0 = r0 * ef0.x, s1 = r2 * ef0.z, s2 = r4 * ef1.x, s3 = r6 * ef1.z;
          s0 = fmaf(r1, ef0.y, s0); s1 = fmaf(r3, ef0.w, s1);
          s2 = fmaf(r5, ef1.y, s2); s3 = fmaf(r7, ef1.w, s3);
          float sv = (s0 + s1) + (s2 + s3);
          sv += __shfl_xor(sv, 1);
          sv += __shfl_xor(sv, 2);
          sv += __shfl_xor(sv, 4);
          float r2j = __shfl(r2sel, j);
          float w = (j < deg) ? expf(sv + r2j) : 0.f;
          ws8[cc] = w;
          den += w;
          // weighted row accumulate into this lane's 8 columns
          const float4* wp = (const float4*)(wl + ((pkj >> 20) & 15) * WLS + (part << 3));
          float4 w0 = wp[0], w1 = wp[1];
          acc0 = fmaf(w * r0, w0.x, acc0);
          acc1 = fmaf(w * r1, w0.y, acc1);
          acc2 = fmaf(w * r2, w0.z, acc2);
          acc3 = fmaf(w * r3, w0.w, acc3);
          acc4 = fmaf(w * r4, w1.x, acc4);
          acc5 = fmaf(w * r5, w1.y, acc5);
          acc6 = fmaf(w * r6, w1.z, acc6);
          acc7 = fmaf(w * r7, w1.w, acc7);
        }
      }
      // full softmax denominator (sum over g: each row counted once per part-octet)
      float den2 = den;
      den2 += __shfl_xor(den2, 8);
      den2 += __shfl_xor(den2, 16);
      den2 += __shfl_xor(den2, 32);
      den2 += 1e-16f;
      float invden = 1.0f / den2;
      // write mask_s (per-chunk: lanes with part==0 write their group's row)
#pragma unroll
      for (int cc = 0; cc < 8; ++cc) {
        if (cc < nch) {
          int j = (cc << 3) + g;
          if (part == 0 && j < deg) mask_s[s + j] = ws8[cc] * invden;
        }
      }
      float aggv = colRT(acc0, acc1, acc2, acc3, acc4, acc5, acc6, acc7, g, part);
      float agg = aggv * invden / (float)deg;
      float nrm = sqrtf(waveReduceSum(agg * agg));
      float val = agg / fmaxf(nrm, 1e-12f);
      ent1bf[o] = f2bf(val);
      out_ent[o] = eh + val;
    } else {
      // ---- generic multi-chunk path (deg>64: essentially never at mean deg 10) ----
      float m2l = -INFINITY;
      for (int base = s; base < e; base += 64) {
        int c = min(64, e - base);
        int pk = (lane < c) ? packed[base + lane] : 0;
        int tb = (pk >> 20) & 15;
        float r2 = rel2t[ent * 9 + ((lane < c) ? tb : 0)];
        int tl = pk & 0xFFFFF;
        const uint4* row = (const uint4*)(ent0bf + (tl << 6));
        const float* ehp = sh_eh[wid];
        float d = 0.f;
#pragma unroll
        for (int q = 0; q < 8; ++q) {
          uint4 a = row[q];
          d += bf2f(a.x & 0xFFFF) * ehp[q * 8 + 0] + bf2f(a.x >> 16) * ehp[q * 8 + 1];
          d += bf2f(a.y & 0xFFFF) * ehp[q * 8 + 2] + bf2f(a.y >> 16) * ehp[q * 8 + 3];
          d += bf2f(a.z & 0xFFFF) * ehp[q * 8 + 4] + bf2f(a.z >> 16) * ehp[q * 8 + 5];
          d += bf2f(a.w & 0xFFFF) * ehp[q * 8 + 6] + bf2f(a.w >> 16) * ehp[q * 8 + 7];
        }
        float trip = d + r2;
        if (lane < c) {
          mask_s[base + lane] = trip;
          m2l = fmaxf(m2l, trip);
        }
      }
      float m2 = waveReduceMax(m2l);
      float denl = 0.f;
      for (int base = s; base < e; base += 64) {
        int c = min(64, e - base);
        denl += (lane < c) ? expf(mask_s[base + lane] - m2) : 0.f;
      }
      float den2 = waveReduceSum(denl) + 1e-16f;
      float acc = 0.f;
      for (int base = s; base < e; base += 64) {
        int c = min(64, e - base);
        int pk = (lane < c) ? packed[base + lane] : 0;
        float mk = 0.f;
        if (lane < c) {
          mk = expf(mask_s[base + lane] - m2) / den2;
          mask_s[base + lane] = mk;
        }
        acc += kg_agg64(c, lane, pk, mk, ent0bf, wl);
      }
      float agg = acc / (float)deg;
      float nrm = sqrtf(waveReduceSum(agg * agg));
      float val = agg / fmaxf(nrm, 1e-12f);
      ent1bf[o] = f2bf(val);
      out_ent[o] = eh + val;
    }
  } else {
    __shared__ float dwl[256];
    __shared__ float latl[256];
    if (threadIdx.x < 256) {
      dwl[threadIdx.x] = dw[threadIdx.x];
      latl[threadIdx.x] = latent[threadIdx.x];
    }
    __syncthreads();
    int usr = (blockIdx.x - KG_BLOCKS) * 4 + wid;  // always < N_USR
    ui_body(usr, lane, ent0bf, sc4, user_emb, out_usr, usr1,
            uptr, cv, dwl, latl, sc4b);
  }
}

// ---------------- D2: KG hop-2 + UI hop-2 (group-layout single-pass) ----------------
__global__ void k_hop2(const ushort_t* __restrict__ srcbf,
                       float* __restrict__ out_ent,
                       const int* __restrict__ hptr, const int* __restrict__ packed,
                       const float* __restrict__ mask_s, const float* __restrict__ weight,
                       const float* __restrict__ usr1, float* __restrict__ out_usr,
                       const int* __restrict__ uptr, const int2* __restrict__ cv,
                       const float4* __restrict__ sc4,
                       const float* __restrict__ dw) {
  int lane = threadIdx.x & 63, wid = threadIdx.x >> 6;
  if (blockIdx.x < KG_BLOCKS) {
    __shared__ __align__(16) float wl[9 * WLS];
    for (int i = threadIdx.x; i < 576; i += 256) wl[(i >> 6) * WLS + (i & 63)] = weight[i];
    __syncthreads();
    int ent = blockIdx.x * 4 + wid;
    int s = hptr[ent], e = hptr[ent + 1];
    int g = lane >> 3, part = lane & 7;
    float a0 = 0.f, a1 = 0.f, a2 = 0.f, a3 = 0.f;
    float a4 = 0.f, a5 = 0.f, a6 = 0.f, a7 = 0.f;
    for (int base = s; base < e; base += 64) {
      int c = min(64, e - base);
      int pk = (lane < c) ? packed[base + lane] : 0;
      float mk = (lane < c) ? mask_s[base + lane] : 0.f;
      int nch = (c + 7) >> 3;
#pragma unroll
      for (int cc = 0; cc < 8; ++cc) {
        if (cc < nch) {
          int j = (cc << 3) + g;
          int pkj = __shfl(pk, j);    // inactive rows: pk=0 -> row 0, mkj=0
          float mkj = __shfl(mk, j);
          uint4 b = *((const uint4*)(srcbf + ((size_t)(pkj & 0xFFFFF) << 6)) + part);
          float r0 = bf2f(b.x & 0xFFFFu), r1 = bf2f(b.x >> 16);
          float r2 = bf2f(b.y & 0xFFFFu), r3 = bf2f(b.y >> 16);
          float r4 = bf2f(b.z & 0xFFFFu), r5 = bf2f(b.z >> 16);
          float r6 = bf2f(b.w & 0xFFFFu), r7 = bf2f(b.w >> 16);
          const float4* wp = (const float4*)(wl + ((pkj >> 20) & 15) * WLS + (part << 3));
          float4 w0 = wp[0], w1 = wp[1];
          a0 = fmaf(mkj * r0, w0.x, a0);
          a1 = fmaf(mkj * r1, w0.y, a1);
          a2 = fmaf(mkj * r2, w0.z, a2);
          a3 = fmaf(mkj * r3, w0.w, a3);
          a4 = fmaf(mkj * r4, w1.x, a4);
          a5 = fmaf(mkj * r5, w1.y, a5);
          a6 = fmaf(mkj * r6, w1.z, a6);
          a7 = fmaf(mkj * r7, w1.w, a7);
        }
      }
    }
    float aggv = colRT(a0, a1, a2, a3, a4, a5, a6, a7, g, part);
    float n = (float)(e - s);
    float agg = aggv / fmaxf(n, 1.0f);
    float nrm = sqrtf(waveReduceSum(agg * agg));
    float val = agg / fmaxf(nrm, 1e-12f);
    size_t o = (size_t)ent * 64 + lane;
    out_ent[o] = out_ent[o] + val;
  } else {
    __shared__ float dwl[256];
    if (threadIdx.x < 256) dwl[threadIdx.x] = dw[threadIdx.x];
    __syncthreads();
    int usr = (blockIdx.x - KG_BLOCKS) * 4 + wid;
    ui_body(usr, lane, srcbf, sc4, out_usr, out_usr, nullptr,
            uptr, cv, dwl, nullptr, nullptr);
  }
}

extern "C" void kernel_launch(void* const* d_in, const int* in_sizes, int n_in,
                              void* d_out, int out_size, void* d_ws, size_t ws_size,
                              hipStream_t stream) {
  const float* user_emb = (const float*)d_in[0];
  const float* entity_emb = (const float*)d_in[1];
  const float* latent = (const float*)d_in[2];
  const float* weight = (const float*)d_in[3];
  const float* disen = (const float*)d_in[4];
  const float* kgW = (const float*)d_in[5];
  const float* ui_vals = (const float*)d_in[6];
  const int* edge_index = (const int*)d_in[7];
  const int* edge_type = (const int*)d_in[8];
  const int* ui_rows = (const int*)d_in[9];
  const int* ui_cols = (const int*)d_in[10];
  const int* head = edge_index;
  const int* tail = edge_index + N_EDGE;

  char* ws = (char*)d_ws;
  size_t o = 0;
  auto alloc = [&](size_t bytes) -> char* {
    char* p = ws + o;
    o += (bytes + 255) & ~(size_t)255;
    return p;
  };
  int* head_ptr = (int*)alloc((N_ENT + 1) * 4);
  int* head_cur = (int*)alloc((size_t)N_ENT * 4);
  int* ui_ptr = (int*)alloc((N_USR + 1) * 4);
  int* ui_cur = (int*)alloc((size_t)N_USR * 4);
  int* bsum_h = (int*)alloc(256 * 4);
  int* bsum_u = (int*)alloc(256 * 4);
  int* packed = (int*)alloc((size_t)N_EDGE * 4);
  int2* cv = (int2*)alloc((size_t)N_EDGE * 8);
  float* mask_s = (float*)alloc((size_t)N_EDGE * 4);
  ushort_t* ent0bf = (ushort_t*)alloc((size_t)N_ENT * 64 * 2);
  ushort_t* ent1bf = (ushort_t*)alloc((size_t)N_ENT * 64 * 2);
  float* usr1 = (float*)alloc((size_t)N_USR * 64 * 4);
  int* cnt9 = (int*)alloc((size_t)N_ENT * 9 * 4);
  float* rel2t = (float*)alloc((size_t)N_ENT * 9 * 4);
  float4* sc4a = (float4*)alloc((size_t)N_USR * 16);
  float4* sc4b = (float4*)alloc((size_t)N_USR * 16);
  float* V = (float*)alloc(9 * 64 * 4);
  float* wsq = (float*)alloc(16 * 4);
  float* dw = (float*)alloc(4 * 64 * 4);
  if (o > ws_size) return;

  float* out_ent = (float*)d_out;
  float* out_usr = out_ent + (size_t)N_ENT * 64;
  float* out_cor = out_ent + (size_t)N_ENT * 64 + (size_t)N_USR * 64;

  hipMemsetAsync(ui_cur, 0, (size_t)N_USR * 4, stream);
  hipMemsetAsync(cnt9, 0, (size_t)N_ENT * 9 * 4, stream);

  // K1: bf16 convert + count + prep + sc(user)
  k_pre<<<TB_BLOCKS + CNT_BLOCKS + 1 + SC_BLOCKS, 256, 0, stream>>>(
      entity_emb, ent0bf, head, ui_rows, edge_type, ui_cur, cnt9,
      weight, kgW, disen, V, wsq, dw, out_cor, user_emb, latent, sc4a);

  int nbh = (N_ENT + 1023) / 1024, nbu = (N_USR + 1023) / 1024;
  // K2: fused scan-reduce
  k_scanred<<<nbh + nbu, 256, 0, stream>>>(cnt9, ui_cur, bsum_h, bsum_u, nbh);
  // K3: block-sum exclusive scans
  k_scan_tops<<<1, 64, 0, stream>>>(bsum_h, nbh, bsum_u, nbu, head_ptr, N_ENT, ui_ptr, N_USR, N_EDGE);
  // K4: fused scan-final
  k_scanfin<<<nbh + nbu, 256, 0, stream>>>(cnt9, bsum_h, bsum_u,
                                           head_ptr, head_cur, ui_ptr, ui_cur, nbh);
  // K5: build + rel2
  k_build_rel2<<<BUILD_BLOCKS + REL2_BLOCKS, 256, 0, stream>>>(
      head, tail, edge_type, ui_rows, ui_cols, ui_vals,
      head_cur, ui_cur, packed, cv, ent0bf, V, wsq, cnt9, rel2t);

  // D1: mask + fused KG hop-1 + UI hop-1 (+ sc4b epilogue)
  k_mask_kg_ui<<<KG_BLOCKS + UI_BLOCKS, 256, 0, stream>>>(
      entity_emb, ent0bf, head_ptr, packed, rel2t, mask_s, weight,
      out_ent, ent1bf, sc4a, out_usr, usr1, ui_ptr, cv, user_emb, dw, latent, sc4b);

  // D2: KG hop-2 + UI hop-2
  k_hop2<<<KG_BLOCKS + UI_BLOCKS, 256, 0, stream>>>(
      ent1bf, out_ent, head_ptr, packed, mask_s, weight,
      usr1, out_usr, ui_ptr, cv, sc4b, dw);
}